// Round 14
// baseline (272.861 us; speedup 1.0000x reference)
//
#include <hip/hip_runtime.h>
#include <hip/hip_bf16.h>
#include <hip/hip_fp16.h>

#define HID 64
#define NGRAPHS 64
#define BUCKET 64        // nodes per bucket (dst >> 6)
#define CAP 4096         // padded entry slots per bucket (mean occupancy ~1024)
#define EPB 2048         // edges per block in bin_scatter (LDS-staged)
#define NL_BLOCKS 512    // node_layer grid (2048 waves)

// ---------------------------------------------------------------------------
// Detect int64 vs int32 for edge_index / batch, init bucket cursors, and
// zero psum/gcnt (pool accumulators). One small dispatch, no memsets.
// ---------------------------------------------------------------------------
__global__ __launch_bounds__(256) void detect_init_kernel(const void* edge, const void* batch,
                                                          int* flags, int* bcursor,
                                                          float* psum, int* gcnt,
                                                          int E2, int N, int G, int NB) {
    int t = threadIdx.x;
    for (int i = t; i < NB; i += 256) bcursor[i] = i * CAP;
    for (int i = t; i < G * HID; i += 256) psum[i] = 0.0f;
    for (int i = t; i < G; i += 256) gcnt[i] = 0;
    if (t < 64) {
        int lane = t;
        int half = E2 / 2;
        int stride = half / 64; if (stride < 1) stride = 1;
        int j = lane * stride; if (j >= half) j = half - 1;
        long long v = ((const long long*)edge)[j];
        bool ok = (v >= 0 && v < (long long)N);
        unsigned long long m = __ballot(ok);
        if (lane == 0) flags[0] = (m == ~0ULL) ? 1 : 0;
        int halfB = N / 2;
        int strideB = halfB / 64; if (strideB < 1) strideB = 1;
        int jb = lane * strideB; if (jb >= halfB) jb = halfB - 1;
        long long vb = ((const long long*)batch)[jb];
        bool okb = (vb >= 0 && vb < (long long)G);
        unsigned long long mb = __ballot(okb);
        if (lane == 0) flags[1] = (mb == ~0ULL) ? 1 : 0;
    }
}

__device__ __forceinline__ int idx_at(const void* p, int i, bool is64) {
    return is64 ? (int)((const long long*)p)[i] : ((const int*)p)[i];
}

// ---------------------------------------------------------------------------
// Bucket scatter into PADDED per-bucket regions, single global read pass:
// stage (src,dst) in LDS while building the histogram, reserve one cursor
// range per bucket, scatter from LDS. entry = (src << 6) | (dst & 63).
// ---------------------------------------------------------------------------
__global__ __launch_bounds__(256) void bin_scatter_kernel(const void* edge, const int* __restrict__ flags,
                                                          int* __restrict__ bcursor,
                                                          unsigned int* __restrict__ entries,
                                                          int E, int NB) {
    extern __shared__ int lds[];    // hist[NB] + base[NB] + ssrc[EPB] + sdst[EPB]
    int* hist = lds;
    int* base = lds + NB;
    int* ssrc = lds + 2 * NB;
    int* sdst = ssrc + EPB;
    for (int i = threadIdx.x; i < NB; i += 256) hist[i] = 0;
    __syncthreads();
    bool is64 = flags[0] != 0;
    int start = blockIdx.x * EPB;
    int end = start + EPB; if (end > E) end = E;
    int cnt = end - start;
    for (int k = threadIdx.x; k < cnt; k += 256) {
        int e = start + k;
        int srcv = idx_at(edge, e, is64);
        int d = idx_at(edge, E + e, is64);
        ssrc[k] = srcv;
        sdst[k] = d;
        atomicAdd(&hist[d >> 6], 1);
    }
    __syncthreads();
    for (int i = threadIdx.x; i < NB; i += 256) {
        int h = hist[i];
        base[i] = h ? atomicAdd(&bcursor[i], h) : 0;   // absolute position
    }
    __syncthreads();
    for (int i = threadIdx.x; i < NB; i += 256) hist[i] = 0;  // reuse as local cursor
    __syncthreads();
    for (int k = threadIdx.x; k < cnt; k += 256) {
        int d = sdst[k];
        int b = d >> 6;
        int lo = atomicAdd(&hist[b], 1);
        int p = base[b] + lo;
        if (p < (b + 1) * CAP)   // overflow guard (statistically unreachable)
            entries[p] = ((unsigned int)ssrc[k] << 6) | (unsigned int)(d & 63);
    }
}

// ---------------------------------------------------------------------------
// Fused CSR finalize + LAYER 1. One block per bucket:
//  pass 1: histogram dests + accumulate x[src] into LDS (scalar feature)
//  wave 0: 64-lane scan -> rowptr (=absolute start in padded csr) + deg
//  pass 2: scatter src into csr within the bucket's padded window
//  phase 3: layer-1 transform -> h1 (fp32 + fp16)
// ---------------------------------------------------------------------------
__global__ __launch_bounds__(256) void csr_l1_kernel(const unsigned int* __restrict__ entries,
                                                     const int* __restrict__ bcursor,
                                                     const float* __restrict__ x,
                                                     const float* __restrict__ W1l,
                                                     const float* __restrict__ b1,
                                                     const float* __restrict__ W1r,
                                                     int* __restrict__ rowptr,
                                                     int* __restrict__ deg,
                                                     int* __restrict__ csr,
                                                     float* __restrict__ h1,
                                                     __half* __restrict__ h1h,
                                                     int N, int NB) {
    __shared__ int hist[BUCKET];
    __shared__ int lstart[BUCKET];
    __shared__ int lcur[BUCKET];
    __shared__ float accx[BUCKET];
    __shared__ float sx[BUCKET];
    int t = threadIdx.x;
    int b = blockIdx.x;
    int r0 = b * CAP;
    int cnt = bcursor[b] - r0; if (cnt > CAP) cnt = CAP;
    if (t < BUCKET) {
        hist[t] = 0; lcur[t] = 0; accx[t] = 0.0f;
        int node = b * BUCKET + t;
        sx[t] = (node < N) ? x[node] : 0.0f;
    }
    __syncthreads();
    for (int j = r0 + t; j < r0 + cnt; j += 256) {
        unsigned int en = entries[j];
        atomicAdd(&hist[en & 63u], 1);
        atomicAdd(&accx[en & 63u], x[en >> 6]);
    }
    __syncthreads();
    if (t < BUCKET) {  // wave 0: inclusive shuffle scan -> exclusive
        int v = hist[t];
        int s = v;
#pragma unroll
        for (int off = 1; off < 64; off <<= 1) {
            int u = __shfl_up(s, off);
            if (t >= off) s += u;
        }
        lstart[t] = s - v;
        int node = b * BUCKET + t;
        if (node < N) {
            rowptr[node] = r0 + s - v;
            deg[node] = v;
        }
    }
    __syncthreads();
    for (int j = r0 + t; j < r0 + cnt; j += 256) {
        unsigned int en = entries[j];
        int dl = (int)(en & 63u);
        int p = atomicAdd(&lcur[dl], 1);
        csr[r0 + lstart[dl] + p] = (int)(en >> 6);
    }
    __syncthreads();
    // Layer-1 transform: 4 subs x 64 features
    int f = t & 63;
    int sub = t >> 6;
    float wlf = W1l[f], bf = b1[f], wrf = W1r[f];
    for (int it = 0; it < 16; ++it) {
        int nl = it * 4 + sub;
        int node = b * BUCKET + nl;
        if (node < N) {
            int d = hist[nl];
            float mv = (d > 0) ? accx[nl] / (float)d : 0.0f;
            float xv = sx[nl];
            float v = fmaf(mv, wlf, fmaf(xv, wrf, bf));
            v = v > 0.0f ? v : 0.0f;
            float hv = v + xv;
            h1[(size_t)node * HID + f] = hv;
            h1h[(size_t)node * HID + f] = __float2half(hv);
        }
    }
}

// ---------------------------------------------------------------------------
// Layers 2/3 aggregation via gather on fp16 rows: 8 lanes per node, each lane
// one uint4 (16 B = 8 halfs). 8x unroll, 4 accumulator banks for MLP.
// ---------------------------------------------------------------------------
__global__ __launch_bounds__(256) void gather_mean_kernel(const int* __restrict__ rowptr,
                                                          const int* __restrict__ deg,
                                                          const int* __restrict__ csr,
                                                          const __half* __restrict__ h,
                                                          float* __restrict__ mean, int N) {
    int grp = threadIdx.x >> 3;      // 32 groups per block
    int l = threadIdx.x & 7;         // lane within group -> 8 features
    int i = blockIdx.x * 32 + grp;
    if (i >= N) return;
    int r0 = rowptr[i];
    int d = deg[i];
    int r1 = r0 + d;
    float a[4][8];
#pragma unroll
    for (int w = 0; w < 4; ++w)
#pragma unroll
        for (int k = 0; k < 8; ++k) a[w][k] = 0.0f;
    int j = r0;
    for (; j + 8 <= r1; j += 8) {
        uint4 u[8];
#pragma unroll
        for (int m = 0; m < 8; ++m) {
            int s = csr[j + m];
            u[m] = *(const uint4*)(h + (size_t)s * HID + l * 8);
        }
#pragma unroll
        for (int m = 0; m < 8; ++m) {
            const __half2* p = (const __half2*)&u[m];
#pragma unroll
            for (int q = 0; q < 4; ++q) {
                float2 f2 = __half22float2(p[q]);
                a[m & 3][2 * q]     += f2.x;
                a[m & 3][2 * q + 1] += f2.y;
            }
        }
    }
    for (; j + 4 <= r1; j += 4) {
        uint4 u[4];
#pragma unroll
        for (int m = 0; m < 4; ++m) {
            int s = csr[j + m];
            u[m] = *(const uint4*)(h + (size_t)s * HID + l * 8);
        }
#pragma unroll
        for (int m = 0; m < 4; ++m) {
            const __half2* p = (const __half2*)&u[m];
#pragma unroll
            for (int q = 0; q < 4; ++q) {
                float2 f2 = __half22float2(p[q]);
                a[m][2 * q]     += f2.x;
                a[m][2 * q + 1] += f2.y;
            }
        }
    }
    for (; j < r1; ++j) {
        int s = csr[j];
        uint4 u0 = *(const uint4*)(h + (size_t)s * HID + l * 8);
        const __half2* p = (const __half2*)&u0;
#pragma unroll
        for (int q = 0; q < 4; ++q) {
            float2 f2 = __half22float2(p[q]);
            a[0][2 * q]     += f2.x;
            a[0][2 * q + 1] += f2.y;
        }
    }
    float inv = (d > 0) ? 1.0f / (float)d : 0.0f;
    float4 o0, o1;
    o0.x = ((a[0][0] + a[1][0]) + (a[2][0] + a[3][0])) * inv;
    o0.y = ((a[0][1] + a[1][1]) + (a[2][1] + a[3][1])) * inv;
    o0.z = ((a[0][2] + a[1][2]) + (a[2][2] + a[3][2])) * inv;
    o0.w = ((a[0][3] + a[1][3]) + (a[2][3] + a[3][3])) * inv;
    o1.x = ((a[0][4] + a[1][4]) + (a[2][4] + a[3][4])) * inv;
    o1.y = ((a[0][5] + a[1][5]) + (a[2][5] + a[3][5])) * inv;
    o1.z = ((a[0][6] + a[1][6]) + (a[2][6] + a[3][6])) * inv;
    o1.w = ((a[0][7] + a[1][7]) + (a[2][7] + a[3][7])) * inv;
    float* mrow = mean + (size_t)i * HID + l * 8;
    *(float4*)(mrow) = o0;
    *(float4*)(mrow + 4) = o1;
}

// ---------------------------------------------------------------------------
// Layers 2/3 node transform — register-weight / scalar-row version.
// __launch_bounds__(256, 2): VGPR cap 256 so wl[64]+wr[64] actually FIT in
// registers (round-11 ran at VGPR=68 -> the weight arrays were spilled to
// scratch, causing 22 MB of re-fetch). Two accumulator chains for 2x FMA ILP.
// ---------------------------------------------------------------------------
__global__ __launch_bounds__(256, 2) void node_layer_kernel(const float* __restrict__ hprev,
                                                            const float* __restrict__ mean,
                                                            const float* __restrict__ Wl,
                                                            const float* __restrict__ bvec,
                                                            const float* __restrict__ Wr,
                                                            float* __restrict__ hout,
                                                            __half* __restrict__ houth,
                                                            int N, int nwaves) {
    int f = threadIdx.x & 63;
    int wid = (blockIdx.x * blockDim.x + threadIdx.x) >> 6;
    float wl[HID], wr[HID];
#pragma unroll
    for (int k = 0; k < HID; ++k) {
        wl[k] = Wl[k * HID + f];
        wr[k] = Wr[k * HID + f];
    }
    float bf = bvec[f];
    for (int i = wid; i < N; i += nwaves) {
        int iu = __builtin_amdgcn_readfirstlane(i);
        const float* mrow = mean + (size_t)iu * HID;
        const float* hrow = hprev + (size_t)iu * HID;
        float hpv = hrow[f];
        float accm = bf;
        float acch = 0.0f;
#pragma unroll
        for (int k = 0; k < HID; ++k) {
            accm = fmaf(mrow[k], wl[k], accm);   // independent chains: 2x ILP
            acch = fmaf(hrow[k], wr[k], acch);
        }
        float acc = accm + acch;
        float r = acc > 0.0f ? acc : 0.0f;
        float hv = r + hpv;
        hout[(size_t)iu * HID + f] = hv;
        if (houth) houth[(size_t)iu * HID + f] = __float2half(hv);
    }
}

// ---------------------------------------------------------------------------
// Global mean pool: batch sorted -> run-length accumulate per wave (782
// waves), one atomic per (graph-run, feature).
// ---------------------------------------------------------------------------
__global__ __launch_bounds__(256) void pool_kernel(const float* __restrict__ h,
                                                   const void* batch,
                                                   const int* __restrict__ flags,
                                                   float* __restrict__ psum,
                                                   int* __restrict__ gcnt,
                                                   int N, int nodesPerWave) {
    int wave = (blockIdx.x * blockDim.x + threadIdx.x) >> 6;
    int f = threadIdx.x & 63;
    int start = wave * nodesPerWave;
    if (start >= N) return;
    bool is64 = flags[1] != 0;
    int end = start + nodesPerWave;
    if (end > N) end = N;
    int g = idx_at(batch, start, is64);
    float acc = 0.0f;
    int c = 0;
    for (int i = start; i < end; ++i) {
        int gi = idx_at(batch, i, is64);
        if (gi != g) {
            atomicAdd(&psum[g * HID + f], acc);
            if (f == 0) atomicAdd(&gcnt[g], c);
            acc = 0.0f; c = 0; g = gi;
        }
        acc += h[(size_t)i * HID + f];
        c++;
    }
    atomicAdd(&psum[g * HID + f], acc);
    if (f == 0) atomicAdd(&gcnt[g], c);
}

// ---------------------------------------------------------------------------
// FC head: one block (64 threads) per graph.
// ---------------------------------------------------------------------------
__global__ __launch_bounds__(64) void fc_kernel(const float* __restrict__ psum,
                                                const int* __restrict__ gcnt,
                                                const float* __restrict__ Wfc1,
                                                const float* __restrict__ bfc1,
                                                const float* __restrict__ Wfc2,
                                                const float* __restrict__ bfc2,
                                                float* __restrict__ out) {
    int g = blockIdx.x;
    int t = threadIdx.x;
    __shared__ float mean[HID];
    float c = fmaxf((float)gcnt[g], 1.0f);
    mean[t] = psum[g * HID + t] / c;
    __syncthreads();
    float v = 0.0f;
    if (t < 32) {
        float acc = bfc1[t];
#pragma unroll
        for (int k = 0; k < HID; ++k) acc += mean[k] * Wfc1[k * 32 + t];
        float hcc = acc > 0.0f ? acc : 0.0f;
        v = hcc * Wfc2[t];
    }
#pragma unroll
    for (int off = 32; off >= 1; off >>= 1) v += __shfl_down(v, off);
    if (t == 0) out[g] = v + bfc2[0];
}

extern "C" void kernel_launch(void* const* d_in, const int* in_sizes, int n_in,
                              void* d_out, int out_size, void* d_ws, size_t ws_size,
                              hipStream_t stream) {
    const int N = in_sizes[0];       // 50000
    const int E2 = in_sizes[1];      // 2*E
    const int E = E2 / 2;
    const int NB = (N + BUCKET - 1) / BUCKET;   // 782

    const float* x    = (const float*)d_in[0];
    const void*  edge = d_in[1];
    const void*  batch= d_in[2];
    const float* W1l  = (const float*)d_in[3];
    const float* b1   = (const float*)d_in[4];
    const float* W1r  = (const float*)d_in[5];
    const float* W2l  = (const float*)d_in[6];
    const float* b2   = (const float*)d_in[7];
    const float* W2r  = (const float*)d_in[8];
    const float* W3l  = (const float*)d_in[9];
    const float* b3   = (const float*)d_in[10];
    const float* W3r  = (const float*)d_in[11];
    const float* Wfc1 = (const float*)d_in[12];
    const float* bfc1 = (const float*)d_in[13];
    const float* Wfc2 = (const float*)d_in[14];
    const float* bfc2 = (const float*)d_in[15];
    float* out = (float*)d_out;

    // Workspace layout (256 B aligned slices). No host-side memsets.
    char* ws = (char*)d_ws;
    size_t o = 0;
    auto alloc = [&](size_t bytes) { char* p = ws + o; o += (bytes + 255) & ~(size_t)255; return p; };
    int*   bcursor = (int*)alloc((size_t)NB * 4);
    float* psum    = (float*)alloc((size_t)NGRAPHS * HID * 4);
    int*   gcnt    = (int*)alloc((size_t)NGRAPHS * 4);
    unsigned int* entries = (unsigned int*)alloc((size_t)NB * CAP * 4);  // padded
    int*   csr     = (int*)alloc((size_t)NB * CAP * 4);                  // padded
    int*   rowptr  = (int*)alloc((size_t)N * 4);
    int*   deg     = (int*)alloc((size_t)N * 4);
    float* h1      = (float*)alloc((size_t)N * HID * 4);   // reused as h3
    float* meanb   = (float*)alloc((size_t)N * HID * 4);
    float* h2      = (float*)alloc((size_t)N * HID * 4);
    __half* h1h    = (__half*)alloc((size_t)N * HID * 2);  // fp16 copy for gather
    __half* h2h    = (__half*)alloc((size_t)N * HID * 2);
    int*   flags   = (int*)alloc(16);
    float* h3 = h1;

    // 1. Detect index dtype + init bucket cursors + zero pool accumulators
    detect_init_kernel<<<1, 256, 0, stream>>>(edge, batch, flags, bcursor, psum, gcnt,
                                              E2, N, NGRAPHS, NB);

    // 2. Single-pass binned scatter (LDS-staged edges) into padded regions
    const int nblk = (E + EPB - 1) / EPB;   // 391
    const int scatter_lds = (2 * NB + 2 * EPB) * 4;   // hist+base+ssrc+sdst
    bin_scatter_kernel<<<nblk, 256, scatter_lds, stream>>>(edge, flags, bcursor, entries, E, NB);

    // 3. Fused CSR finalize + layer 1
    csr_l1_kernel<<<NB, 256, 0, stream>>>(entries, bcursor, x, W1l, b1, W1r,
                                          rowptr, deg, csr, h1, h1h, N, NB);

    const int nlWaves = NL_BLOCKS * 4;

    // 4-5. Layer 2
    gather_mean_kernel<<<(N + 31) / 32, 256, 0, stream>>>(rowptr, deg, csr, h1h, meanb, N);
    node_layer_kernel<<<NL_BLOCKS, 256, 0, stream>>>(h1, meanb, W2l, b2, W2r, h2, h2h, N, nlWaves);

    // 6-7. Layer 3 (no fp16 copy needed — nothing gathers from h3)
    gather_mean_kernel<<<(N + 31) / 32, 256, 0, stream>>>(rowptr, deg, csr, h2h, meanb, N);
    node_layer_kernel<<<NL_BLOCKS, 256, 0, stream>>>(h2, meanb, W3l, b3, W3r, h3, (__half*)nullptr, N, nlWaves);

    // 8. Wave-parallel pool (batch sorted -> run-length + atomics)
    {
        int nodesPerWave = 64;
        int waves = (N + nodesPerWave - 1) / nodesPerWave;
        int threads = waves * 64;
        pool_kernel<<<(threads + 255) / 256, 256, 0, stream>>>(h3, batch, flags, psum, gcnt,
                                                               N, nodesPerWave);
    }
    // 9. FC head
    fc_kernel<<<NGRAPHS, 64, 0, stream>>>(psum, gcnt, Wfc1, bfc1, Wfc2, bfc2, out);
}

// Round 15
// 244.533 us; speedup vs baseline: 1.1158x; 1.1158x over previous
//
#include <hip/hip_runtime.h>
#include <hip/hip_bf16.h>
#include <hip/hip_fp16.h>

#define HID 64
#define NGRAPHS 64
#define BUCKET 64        // nodes per bucket (dst >> 6)
#define CAP 4096         // padded entry slots per bucket (mean occupancy ~1024)
#define EPB 2048         // edges per block in bin_scatter (LDS-staged)

typedef _Float16 half8 __attribute__((ext_vector_type(8)));
typedef float floatx4 __attribute__((ext_vector_type(4)));

// ---------------------------------------------------------------------------
// Detect int64 vs int32, init bucket cursors, zero pool accumulators, and
// convert layer-2/3 weights to fp16 for the MFMA path.
// ---------------------------------------------------------------------------
__global__ __launch_bounds__(256) void detect_init_kernel(const void* edge, const void* batch,
                                                          int* flags, int* bcursor,
                                                          float* psum, int* gcnt,
                                                          const float* W2l, const float* W2r,
                                                          const float* W3l, const float* W3r,
                                                          __half* wl2h, __half* wr2h,
                                                          __half* wl3h, __half* wr3h,
                                                          int E2, int N, int G, int NB) {
    int t = threadIdx.x;
    for (int i = t; i < NB; i += 256) bcursor[i] = i * CAP;
    for (int i = t; i < G * HID; i += 256) psum[i] = 0.0f;
    for (int i = t; i < G; i += 256) gcnt[i] = 0;
    for (int i = t; i < HID * HID; i += 256) {
        wl2h[i] = __float2half(W2l[i]);
        wr2h[i] = __float2half(W2r[i]);
        wl3h[i] = __float2half(W3l[i]);
        wr3h[i] = __float2half(W3r[i]);
    }
    if (t < 64) {
        int lane = t;
        int half_ = E2 / 2;
        int stride = half_ / 64; if (stride < 1) stride = 1;
        int j = lane * stride; if (j >= half_) j = half_ - 1;
        long long v = ((const long long*)edge)[j];
        bool ok = (v >= 0 && v < (long long)N);
        unsigned long long m = __ballot(ok);
        if (lane == 0) flags[0] = (m == ~0ULL) ? 1 : 0;
        int halfB = N / 2;
        int strideB = halfB / 64; if (strideB < 1) strideB = 1;
        int jb = lane * strideB; if (jb >= halfB) jb = halfB - 1;
        long long vb = ((const long long*)batch)[jb];
        bool okb = (vb >= 0 && vb < (long long)G);
        unsigned long long mb = __ballot(okb);
        if (lane == 0) flags[1] = (mb == ~0ULL) ? 1 : 0;
    }
}

__device__ __forceinline__ int idx_at(const void* p, int i, bool is64) {
    return is64 ? (int)((const long long*)p)[i] : ((const int*)p)[i];
}

// ---------------------------------------------------------------------------
// Bucket scatter into PADDED per-bucket regions, single global read pass.
// entry = (src << 6) | (dst & 63).
// ---------------------------------------------------------------------------
__global__ __launch_bounds__(256) void bin_scatter_kernel(const void* edge, const int* __restrict__ flags,
                                                          int* __restrict__ bcursor,
                                                          unsigned int* __restrict__ entries,
                                                          int E, int NB) {
    extern __shared__ int lds[];    // hist[NB] + base[NB] + ssrc[EPB] + sdst[EPB]
    int* hist = lds;
    int* base = lds + NB;
    int* ssrc = lds + 2 * NB;
    int* sdst = ssrc + EPB;
    for (int i = threadIdx.x; i < NB; i += 256) hist[i] = 0;
    __syncthreads();
    bool is64 = flags[0] != 0;
    int start = blockIdx.x * EPB;
    int end = start + EPB; if (end > E) end = E;
    int cnt = end - start;
    for (int k = threadIdx.x; k < cnt; k += 256) {
        int e = start + k;
        int srcv = idx_at(edge, e, is64);
        int d = idx_at(edge, E + e, is64);
        ssrc[k] = srcv;
        sdst[k] = d;
        atomicAdd(&hist[d >> 6], 1);
    }
    __syncthreads();
    for (int i = threadIdx.x; i < NB; i += 256) {
        int h = hist[i];
        base[i] = h ? atomicAdd(&bcursor[i], h) : 0;   // absolute position
    }
    __syncthreads();
    for (int i = threadIdx.x; i < NB; i += 256) hist[i] = 0;  // reuse as local cursor
    __syncthreads();
    for (int k = threadIdx.x; k < cnt; k += 256) {
        int d = sdst[k];
        int b = d >> 6;
        int lo = atomicAdd(&hist[b], 1);
        int p = base[b] + lo;
        if (p < (b + 1) * CAP)   // overflow guard (statistically unreachable)
            entries[p] = ((unsigned int)ssrc[k] << 6) | (unsigned int)(d & 63);
    }
}

// ---------------------------------------------------------------------------
// Fused CSR finalize + LAYER 1 (unchanged, proven).
// ---------------------------------------------------------------------------
__global__ __launch_bounds__(256) void csr_l1_kernel(const unsigned int* __restrict__ entries,
                                                     const int* __restrict__ bcursor,
                                                     const float* __restrict__ x,
                                                     const float* __restrict__ W1l,
                                                     const float* __restrict__ b1,
                                                     const float* __restrict__ W1r,
                                                     int* __restrict__ rowptr,
                                                     int* __restrict__ deg,
                                                     int* __restrict__ csr,
                                                     float* __restrict__ h1,
                                                     __half* __restrict__ h1h,
                                                     int N, int NB) {
    __shared__ int hist[BUCKET];
    __shared__ int lstart[BUCKET];
    __shared__ int lcur[BUCKET];
    __shared__ float accx[BUCKET];
    __shared__ float sx[BUCKET];
    int t = threadIdx.x;
    int b = blockIdx.x;
    int r0 = b * CAP;
    int cnt = bcursor[b] - r0; if (cnt > CAP) cnt = CAP;
    if (t < BUCKET) {
        hist[t] = 0; lcur[t] = 0; accx[t] = 0.0f;
        int node = b * BUCKET + t;
        sx[t] = (node < N) ? x[node] : 0.0f;
    }
    __syncthreads();
    for (int j = r0 + t; j < r0 + cnt; j += 256) {
        unsigned int en = entries[j];
        atomicAdd(&hist[en & 63u], 1);
        atomicAdd(&accx[en & 63u], x[en >> 6]);
    }
    __syncthreads();
    if (t < BUCKET) {  // wave 0: inclusive shuffle scan -> exclusive
        int v = hist[t];
        int s = v;
#pragma unroll
        for (int off = 1; off < 64; off <<= 1) {
            int u = __shfl_up(s, off);
            if (t >= off) s += u;
        }
        lstart[t] = s - v;
        int node = b * BUCKET + t;
        if (node < N) {
            rowptr[node] = r0 + s - v;
            deg[node] = v;
        }
    }
    __syncthreads();
    for (int j = r0 + t; j < r0 + cnt; j += 256) {
        unsigned int en = entries[j];
        int dl = (int)(en & 63u);
        int p = atomicAdd(&lcur[dl], 1);
        csr[r0 + lstart[dl] + p] = (int)(en >> 6);
    }
    __syncthreads();
    // Layer-1 transform: 4 subs x 64 features
    int f = t & 63;
    int sub = t >> 6;
    float wlf = W1l[f], bf = b1[f], wrf = W1r[f];
    for (int it = 0; it < 16; ++it) {
        int nl = it * 4 + sub;
        int node = b * BUCKET + nl;
        if (node < N) {
            int d = hist[nl];
            float mv = (d > 0) ? accx[nl] / (float)d : 0.0f;
            float xv = sx[nl];
            float v = fmaf(mv, wlf, fmaf(xv, wrf, bf));
            v = v > 0.0f ? v : 0.0f;
            float hv = v + xv;
            h1[(size_t)node * HID + f] = hv;
            h1h[(size_t)node * HID + f] = __float2half(hv);
        }
    }
}

// ---------------------------------------------------------------------------
// Layers 2/3 aggregation via gather on fp16 rows: 8 lanes per node, each lane
// one uint4 (16 B = 8 halfs). 8x unroll. Mean now STORED AS FP16 (MFMA input).
// ---------------------------------------------------------------------------
__global__ __launch_bounds__(256) void gather_mean_kernel(const int* __restrict__ rowptr,
                                                          const int* __restrict__ deg,
                                                          const int* __restrict__ csr,
                                                          const __half* __restrict__ h,
                                                          __half* __restrict__ mean, int N) {
    int grp = threadIdx.x >> 3;      // 32 groups per block
    int l = threadIdx.x & 7;         // lane within group -> 8 features
    int i = blockIdx.x * 32 + grp;
    if (i >= N) return;
    int r0 = rowptr[i];
    int d = deg[i];
    int r1 = r0 + d;
    float a[4][8];
#pragma unroll
    for (int w = 0; w < 4; ++w)
#pragma unroll
        for (int k = 0; k < 8; ++k) a[w][k] = 0.0f;
    int j = r0;
    for (; j + 8 <= r1; j += 8) {
        uint4 u[8];
#pragma unroll
        for (int m = 0; m < 8; ++m) {
            int s = csr[j + m];
            u[m] = *(const uint4*)(h + (size_t)s * HID + l * 8);
        }
#pragma unroll
        for (int m = 0; m < 8; ++m) {
            const __half2* p = (const __half2*)&u[m];
#pragma unroll
            for (int q = 0; q < 4; ++q) {
                float2 f2 = __half22float2(p[q]);
                a[m & 3][2 * q]     += f2.x;
                a[m & 3][2 * q + 1] += f2.y;
            }
        }
    }
    for (; j + 4 <= r1; j += 4) {
        uint4 u[4];
#pragma unroll
        for (int m = 0; m < 4; ++m) {
            int s = csr[j + m];
            u[m] = *(const uint4*)(h + (size_t)s * HID + l * 8);
        }
#pragma unroll
        for (int m = 0; m < 4; ++m) {
            const __half2* p = (const __half2*)&u[m];
#pragma unroll
            for (int q = 0; q < 4; ++q) {
                float2 f2 = __half22float2(p[q]);
                a[m][2 * q]     += f2.x;
                a[m][2 * q + 1] += f2.y;
            }
        }
    }
    for (; j < r1; ++j) {
        int s = csr[j];
        uint4 u0 = *(const uint4*)(h + (size_t)s * HID + l * 8);
        const __half2* p = (const __half2*)&u0;
#pragma unroll
        for (int q = 0; q < 4; ++q) {
            float2 f2 = __half22float2(p[q]);
            a[0][2 * q]     += f2.x;
            a[0][2 * q + 1] += f2.y;
        }
    }
    float inv = (d > 0) ? 1.0f / (float)d : 0.0f;
    __half2 o[4];
#pragma unroll
    for (int q = 0; q < 4; ++q) {
        float lo = ((a[0][2*q]   + a[1][2*q])   + (a[2][2*q]   + a[3][2*q]))   * inv;
        float hi = ((a[0][2*q+1] + a[1][2*q+1]) + (a[2][2*q+1] + a[3][2*q+1])) * inv;
        o[q] = __floats2half2_rn(lo, hi);
    }
    *(uint4*)(mean + (size_t)i * HID + l * 8) = *(uint4*)o;
}

// ---------------------------------------------------------------------------
// Layers 2/3 node transform via MFMA. One wave per 16-node tile.
// D[16 nodes x 64 feat] = Mean_f16·Wl_f16 + Hp_f16·Wr_f16 + b  (fp32 acc),
// then relu + fp32 residual. Layouts (gfx950 mfma_f32_16x16x32_f16):
//   A: A[m=lane&15][k=(lane>>4)*8+j]   B: B[k=(lane>>4)*8+j][n=lane&15]
//   C/D: col=lane&15, row=(lane>>4)*4+reg   [measured: learn_hip m89/m91]
// ---------------------------------------------------------------------------
__global__ __launch_bounds__(256) void node_layer_mfma_kernel(const __half* __restrict__ meanh,
                                                              const __half* __restrict__ hph,
                                                              const float* __restrict__ hpf,
                                                              const __half* __restrict__ Wlh,
                                                              const float* __restrict__ bvec,
                                                              const __half* __restrict__ Wrh,
                                                              float* __restrict__ hout,
                                                              __half* __restrict__ houth,
                                                              int N) {
    int wave = threadIdx.x >> 6;
    int lane = threadIdx.x & 63;
    int group = blockIdx.x * 4 + wave;      // 16-node tile
    int node0 = group * 16;
    if (node0 >= N) return;
    int m = lane & 15;
    int quad = lane >> 4;

    // B fragments (weights): 16 frags x 8 halfs; W is 8 KB -> L1-resident
    const _Float16* wlp = (const _Float16*)Wlh;
    const _Float16* wrp = (const _Float16*)Wrh;
    half8 bl[2][4], br[2][4];
#pragma unroll
    for (int kh = 0; kh < 2; ++kh)
#pragma unroll
        for (int nt = 0; nt < 4; ++nt) {
            half8 vl, vr;
#pragma unroll
            for (int j = 0; j < 8; ++j) {
                int k = kh * 32 + quad * 8 + j;
                vl[j] = wlp[k * HID + nt * 16 + m];
                vr[j] = wrp[k * HID + nt * 16 + m];
            }
            bl[kh][nt] = vl;
            br[kh][nt] = vr;
        }

    // A fragments: row m of the tile (mean + hprev, fp16)
    int nodeA = node0 + m; if (nodeA >= N) nodeA = N - 1;
    const _Float16* mrow = (const _Float16*)meanh + (size_t)nodeA * HID;
    const _Float16* hrow = (const _Float16*)hph + (size_t)nodeA * HID;
    half8 am0 = *(const half8*)(mrow + quad * 8);
    half8 am1 = *(const half8*)(mrow + 32 + quad * 8);
    half8 ah0 = *(const half8*)(hrow + quad * 8);
    half8 ah1 = *(const half8*)(hrow + 32 + quad * 8);

#pragma unroll
    for (int nt = 0; nt < 4; ++nt) {
        float b = bvec[nt * 16 + m];        // bias depends on col only
        floatx4 c = {b, b, b, b};
        c = __builtin_amdgcn_mfma_f32_16x16x32_f16(am0, bl[0][nt], c, 0, 0, 0);
        c = __builtin_amdgcn_mfma_f32_16x16x32_f16(am1, bl[1][nt], c, 0, 0, 0);
        c = __builtin_amdgcn_mfma_f32_16x16x32_f16(ah0, br[0][nt], c, 0, 0, 0);
        c = __builtin_amdgcn_mfma_f32_16x16x32_f16(ah1, br[1][nt], c, 0, 0, 0);
#pragma unroll
        for (int r = 0; r < 4; ++r) {
            int nodeR = node0 + quad * 4 + r;
            if (nodeR < N) {
                int f = nt * 16 + m;
                float v = c[r];
                v = v > 0.0f ? v : 0.0f;
                float hv = v + hpf[(size_t)nodeR * HID + f];   // exact fp32 residual
                hout[(size_t)nodeR * HID + f] = hv;
                if (houth) houth[(size_t)nodeR * HID + f] = __float2half(hv);
            }
        }
    }
}

// ---------------------------------------------------------------------------
// Global mean pool: batch sorted -> run-length accumulate per wave.
// ---------------------------------------------------------------------------
__global__ __launch_bounds__(256) void pool_kernel(const float* __restrict__ h,
                                                   const void* batch,
                                                   const int* __restrict__ flags,
                                                   float* __restrict__ psum,
                                                   int* __restrict__ gcnt,
                                                   int N, int nodesPerWave) {
    int wave = (blockIdx.x * blockDim.x + threadIdx.x) >> 6;
    int f = threadIdx.x & 63;
    int start = wave * nodesPerWave;
    if (start >= N) return;
    bool is64 = flags[1] != 0;
    int end = start + nodesPerWave;
    if (end > N) end = N;
    int g = idx_at(batch, start, is64);
    float acc = 0.0f;
    int c = 0;
    for (int i = start; i < end; ++i) {
        int gi = idx_at(batch, i, is64);
        if (gi != g) {
            atomicAdd(&psum[g * HID + f], acc);
            if (f == 0) atomicAdd(&gcnt[g], c);
            acc = 0.0f; c = 0; g = gi;
        }
        acc += h[(size_t)i * HID + f];
        c++;
    }
    atomicAdd(&psum[g * HID + f], acc);
    if (f == 0) atomicAdd(&gcnt[g], c);
}

// ---------------------------------------------------------------------------
// FC head: one block (64 threads) per graph.
// ---------------------------------------------------------------------------
__global__ __launch_bounds__(64) void fc_kernel(const float* __restrict__ psum,
                                                const int* __restrict__ gcnt,
                                                const float* __restrict__ Wfc1,
                                                const float* __restrict__ bfc1,
                                                const float* __restrict__ Wfc2,
                                                const float* __restrict__ bfc2,
                                                float* __restrict__ out) {
    int g = blockIdx.x;
    int t = threadIdx.x;
    __shared__ float mean[HID];
    float c = fmaxf((float)gcnt[g], 1.0f);
    mean[t] = psum[g * HID + t] / c;
    __syncthreads();
    float v = 0.0f;
    if (t < 32) {
        float acc = bfc1[t];
#pragma unroll
        for (int k = 0; k < HID; ++k) acc += mean[k] * Wfc1[k * 32 + t];
        float hcc = acc > 0.0f ? acc : 0.0f;
        v = hcc * Wfc2[t];
    }
#pragma unroll
    for (int off = 32; off >= 1; off >>= 1) v += __shfl_down(v, off);
    if (t == 0) out[g] = v + bfc2[0];
}

extern "C" void kernel_launch(void* const* d_in, const int* in_sizes, int n_in,
                              void* d_out, int out_size, void* d_ws, size_t ws_size,
                              hipStream_t stream) {
    const int N = in_sizes[0];       // 50000
    const int E2 = in_sizes[1];      // 2*E
    const int E = E2 / 2;
    const int NB = (N + BUCKET - 1) / BUCKET;   // 782

    const float* x    = (const float*)d_in[0];
    const void*  edge = d_in[1];
    const void*  batch= d_in[2];
    const float* W1l  = (const float*)d_in[3];
    const float* b1   = (const float*)d_in[4];
    const float* W1r  = (const float*)d_in[5];
    const float* W2l  = (const float*)d_in[6];
    const float* b2   = (const float*)d_in[7];
    const float* W2r  = (const float*)d_in[8];
    const float* W3l  = (const float*)d_in[9];
    const float* b3   = (const float*)d_in[10];
    const float* W3r  = (const float*)d_in[11];
    const float* Wfc1 = (const float*)d_in[12];
    const float* bfc1 = (const float*)d_in[13];
    const float* Wfc2 = (const float*)d_in[14];
    const float* bfc2 = (const float*)d_in[15];
    float* out = (float*)d_out;

    // Workspace layout (256 B aligned slices). No host-side memsets.
    char* ws = (char*)d_ws;
    size_t o = 0;
    auto alloc = [&](size_t bytes) { char* p = ws + o; o += (bytes + 255) & ~(size_t)255; return p; };
    int*   bcursor = (int*)alloc((size_t)NB * 4);
    float* psum    = (float*)alloc((size_t)NGRAPHS * HID * 4);
    int*   gcnt    = (int*)alloc((size_t)NGRAPHS * 4);
    unsigned int* entries = (unsigned int*)alloc((size_t)NB * CAP * 4);  // padded
    int*   csr     = (int*)alloc((size_t)NB * CAP * 4);                  // padded
    int*   rowptr  = (int*)alloc((size_t)N * 4);
    int*   deg     = (int*)alloc((size_t)N * 4);
    float* h1      = (float*)alloc((size_t)N * HID * 4);   // reused as h3
    float* h2      = (float*)alloc((size_t)N * HID * 4);
    __half* meanbh = (__half*)alloc((size_t)N * HID * 2);  // fp16 mean (MFMA A)
    __half* h1h    = (__half*)alloc((size_t)N * HID * 2);  // fp16 copies
    __half* h2h    = (__half*)alloc((size_t)N * HID * 2);
    __half* wl2h   = (__half*)alloc((size_t)HID * HID * 2);
    __half* wr2h   = (__half*)alloc((size_t)HID * HID * 2);
    __half* wl3h   = (__half*)alloc((size_t)HID * HID * 2);
    __half* wr3h   = (__half*)alloc((size_t)HID * HID * 2);
    int*   flags   = (int*)alloc(16);
    float* h3 = h1;

    // 1. Detect index dtype + init cursors/accumulators + fp16 weight convert
    detect_init_kernel<<<1, 256, 0, stream>>>(edge, batch, flags, bcursor, psum, gcnt,
                                              W2l, W2r, W3l, W3r, wl2h, wr2h, wl3h, wr3h,
                                              E2, N, NGRAPHS, NB);

    // 2. Single-pass binned scatter (LDS-staged edges) into padded regions
    const int nblk = (E + EPB - 1) / EPB;   // 391
    const int scatter_lds = (2 * NB + 2 * EPB) * 4;   // hist+base+ssrc+sdst
    bin_scatter_kernel<<<nblk, 256, scatter_lds, stream>>>(edge, flags, bcursor, entries, E, NB);

    // 3. Fused CSR finalize + layer 1
    csr_l1_kernel<<<NB, 256, 0, stream>>>(entries, bcursor, x, W1l, b1, W1r,
                                          rowptr, deg, csr, h1, h1h, N, NB);

    const int ngroups = (N + 15) / 16;        // 3125 16-node tiles
    const int nlBlocks = (ngroups + 3) / 4;   // 782 blocks x 4 waves

    // 4-5. Layer 2
    gather_mean_kernel<<<(N + 31) / 32, 256, 0, stream>>>(rowptr, deg, csr, h1h, meanbh, N);
    node_layer_mfma_kernel<<<nlBlocks, 256, 0, stream>>>(meanbh, h1h, h1, wl2h, b2, wr2h,
                                                         h2, h2h, N);

    // 6-7. Layer 3 (no fp16 output copy — nothing gathers from h3)
    gather_mean_kernel<<<(N + 31) / 32, 256, 0, stream>>>(rowptr, deg, csr, h2h, meanbh, N);
    node_layer_mfma_kernel<<<nlBlocks, 256, 0, stream>>>(meanbh, h2h, h2, wl3h, b3, wr3h,
                                                         h3, (__half*)nullptr, N);

    // 8. Wave-parallel pool (batch sorted -> run-length + atomics)
    {
        int nodesPerWave = 64;
        int waves = (N + nodesPerWave - 1) / nodesPerWave;
        int threads = waves * 64;
        pool_kernel<<<(threads + 255) / 256, 256, 0, stream>>>(h3, batch, flags, psum, gcnt,
                                                               N, nodesPerWave);
    }
    // 9. FC head
    fc_kernel<<<NGRAPHS, 64, 0, stream>>>(psum, gcnt, Wfc1, bfc1, Wfc2, bfc2, out);
}

// Round 16
// 241.023 us; speedup vs baseline: 1.1321x; 1.0146x over previous
//
#include <hip/hip_runtime.h>
#include <hip/hip_bf16.h>
#include <hip/hip_fp16.h>

#define HID 64
#define NGRAPHS 64
#define BUCKET 64        // nodes per bucket (dst >> 6)
#define CAP 4096         // padded entry slots per bucket (mean occupancy ~1024)
#define EPB 2048         // edges per block in bin_scatter (LDS-staged)

typedef _Float16 half8 __attribute__((ext_vector_type(8)));
typedef float floatx4 __attribute__((ext_vector_type(4)));

// ---------------------------------------------------------------------------
// Detect int64 vs int32, init bucket cursors, zero pool accumulators, and
// convert layer-2/3 weights to fp16 for the MFMA path.
// ---------------------------------------------------------------------------
__global__ __launch_bounds__(256) void detect_init_kernel(const void* edge, const void* batch,
                                                          int* flags, int* bcursor,
                                                          float* psum, int* gcnt,
                                                          const float* W2l, const float* W2r,
                                                          const float* W3l, const float* W3r,
                                                          __half* wl2h, __half* wr2h,
                                                          __half* wl3h, __half* wr3h,
                                                          int E2, int N, int G, int NB) {
    int t = threadIdx.x;
    for (int i = t; i < NB; i += 256) bcursor[i] = i * CAP;
    for (int i = t; i < G * HID; i += 256) psum[i] = 0.0f;
    for (int i = t; i < G; i += 256) gcnt[i] = 0;
    for (int i = t; i < HID * HID; i += 256) {
        wl2h[i] = __float2half(W2l[i]);
        wr2h[i] = __float2half(W2r[i]);
        wl3h[i] = __float2half(W3l[i]);
        wr3h[i] = __float2half(W3r[i]);
    }
    if (t < 64) {
        int lane = t;
        int half_ = E2 / 2;
        int stride = half_ / 64; if (stride < 1) stride = 1;
        int j = lane * stride; if (j >= half_) j = half_ - 1;
        long long v = ((const long long*)edge)[j];
        bool ok = (v >= 0 && v < (long long)N);
        unsigned long long m = __ballot(ok);
        if (lane == 0) flags[0] = (m == ~0ULL) ? 1 : 0;
        int halfB = N / 2;
        int strideB = halfB / 64; if (strideB < 1) strideB = 1;
        int jb = lane * strideB; if (jb >= halfB) jb = halfB - 1;
        long long vb = ((const long long*)batch)[jb];
        bool okb = (vb >= 0 && vb < (long long)G);
        unsigned long long mb = __ballot(okb);
        if (lane == 0) flags[1] = (mb == ~0ULL) ? 1 : 0;
    }
}

__device__ __forceinline__ int idx_at(const void* p, int i, bool is64) {
    return is64 ? (int)((const long long*)p)[i] : ((const int*)p)[i];
}

// ---------------------------------------------------------------------------
// Bucket scatter into PADDED per-bucket regions, single global read pass.
// entry = (src << 6) | (dst & 63).
// ---------------------------------------------------------------------------
__global__ __launch_bounds__(256) void bin_scatter_kernel(const void* edge, const int* __restrict__ flags,
                                                          int* __restrict__ bcursor,
                                                          unsigned int* __restrict__ entries,
                                                          int E, int NB) {
    extern __shared__ int lds[];    // hist[NB] + base[NB] + ssrc[EPB] + sdst[EPB]
    int* hist = lds;
    int* base = lds + NB;
    int* ssrc = lds + 2 * NB;
    int* sdst = ssrc + EPB;
    for (int i = threadIdx.x; i < NB; i += 256) hist[i] = 0;
    __syncthreads();
    bool is64 = flags[0] != 0;
    int start = blockIdx.x * EPB;
    int end = start + EPB; if (end > E) end = E;
    int cnt = end - start;
    for (int k = threadIdx.x; k < cnt; k += 256) {
        int e = start + k;
        int srcv = idx_at(edge, e, is64);
        int d = idx_at(edge, E + e, is64);
        ssrc[k] = srcv;
        sdst[k] = d;
        atomicAdd(&hist[d >> 6], 1);
    }
    __syncthreads();
    for (int i = threadIdx.x; i < NB; i += 256) {
        int h = hist[i];
        base[i] = h ? atomicAdd(&bcursor[i], h) : 0;   // absolute position
    }
    __syncthreads();
    for (int i = threadIdx.x; i < NB; i += 256) hist[i] = 0;  // reuse as local cursor
    __syncthreads();
    for (int k = threadIdx.x; k < cnt; k += 256) {
        int d = sdst[k];
        int b = d >> 6;
        int lo = atomicAdd(&hist[b], 1);
        int p = base[b] + lo;
        if (p < (b + 1) * CAP)   // overflow guard (statistically unreachable)
            entries[p] = ((unsigned int)ssrc[k] << 6) | (unsigned int)(d & 63);
    }
}

// ---------------------------------------------------------------------------
// Fused CSR finalize + LAYER 1 (unchanged, proven).
// ---------------------------------------------------------------------------
__global__ __launch_bounds__(256) void csr_l1_kernel(const unsigned int* __restrict__ entries,
                                                     const int* __restrict__ bcursor,
                                                     const float* __restrict__ x,
                                                     const float* __restrict__ W1l,
                                                     const float* __restrict__ b1,
                                                     const float* __restrict__ W1r,
                                                     int* __restrict__ rowptr,
                                                     int* __restrict__ deg,
                                                     int* __restrict__ csr,
                                                     float* __restrict__ h1,
                                                     __half* __restrict__ h1h,
                                                     int N, int NB) {
    __shared__ int hist[BUCKET];
    __shared__ int lstart[BUCKET];
    __shared__ int lcur[BUCKET];
    __shared__ float accx[BUCKET];
    __shared__ float sx[BUCKET];
    int t = threadIdx.x;
    int b = blockIdx.x;
    int r0 = b * CAP;
    int cnt = bcursor[b] - r0; if (cnt > CAP) cnt = CAP;
    if (t < BUCKET) {
        hist[t] = 0; lcur[t] = 0; accx[t] = 0.0f;
        int node = b * BUCKET + t;
        sx[t] = (node < N) ? x[node] : 0.0f;
    }
    __syncthreads();
    for (int j = r0 + t; j < r0 + cnt; j += 256) {
        unsigned int en = entries[j];
        atomicAdd(&hist[en & 63u], 1);
        atomicAdd(&accx[en & 63u], x[en >> 6]);
    }
    __syncthreads();
    if (t < BUCKET) {  // wave 0: inclusive shuffle scan -> exclusive
        int v = hist[t];
        int s = v;
#pragma unroll
        for (int off = 1; off < 64; off <<= 1) {
            int u = __shfl_up(s, off);
            if (t >= off) s += u;
        }
        lstart[t] = s - v;
        int node = b * BUCKET + t;
        if (node < N) {
            rowptr[node] = r0 + s - v;
            deg[node] = v;
        }
    }
    __syncthreads();
    for (int j = r0 + t; j < r0 + cnt; j += 256) {
        unsigned int en = entries[j];
        int dl = (int)(en & 63u);
        int p = atomicAdd(&lcur[dl], 1);
        csr[r0 + lstart[dl] + p] = (int)(en >> 6);
    }
    __syncthreads();
    // Layer-1 transform: 4 subs x 64 features
    int f = t & 63;
    int sub = t >> 6;
    float wlf = W1l[f], bf = b1[f], wrf = W1r[f];
    for (int it = 0; it < 16; ++it) {
        int nl = it * 4 + sub;
        int node = b * BUCKET + nl;
        if (node < N) {
            int d = hist[nl];
            float mv = (d > 0) ? accx[nl] / (float)d : 0.0f;
            float xv = sx[nl];
            float v = fmaf(mv, wlf, fmaf(xv, wrf, bf));
            v = v > 0.0f ? v : 0.0f;
            float hv = v + xv;
            h1[(size_t)node * HID + f] = hv;
            h1h[(size_t)node * HID + f] = __float2half(hv);
        }
    }
}

// ---------------------------------------------------------------------------
// FUSED gather + MFMA node transform. 32 nodes per 256-thread block.
// Phase 1: 8 lanes/node gather fp16 neighbor rows -> fp32 acc -> fp16 mean
//          into padded LDS tile (72-half rows: 16B-aligned, A-reads 2-way).
// Phase 2: waves 0-1 run the MFMA transform (16 nodes each):
//   D = Mean_f16·Wl_f16 + Hp_f16·Wr_f16 + b (fp32 acc), relu, fp32 residual.
// Layouts (gfx950 mfma_f32_16x16x32_f16): A[m=lane&15][k=quad*8+j],
// B[k=quad*8+j][n=lane&15], C/D col=lane&15 row=quad*4+reg  [m89/m91].
// ---------------------------------------------------------------------------
__global__ __launch_bounds__(256) void gather_mfma_kernel(const int* __restrict__ rowptr,
                                                          const int* __restrict__ deg,
                                                          const int* __restrict__ csr,
                                                          const __half* __restrict__ hph,
                                                          const float* __restrict__ hpf,
                                                          const __half* __restrict__ Wlh,
                                                          const float* __restrict__ bvec,
                                                          const __half* __restrict__ Wrh,
                                                          float* __restrict__ hout,
                                                          __half* __restrict__ houth,
                                                          int N) {
    __shared__ _Float16 smean[32][HID + 8];   // 72-half rows (144 B, 16B-aligned)
    int t = threadIdx.x;

    // ---- Phase 1: gather means (8 lanes/node x 32 nodes) ----
    {
        int grp = t >> 3;        // 0..31 -> node local
        int l = t & 7;           // 8 features x 8 halfs per lane
        int i = blockIdx.x * 32 + grp;
        if (i < N) {
            int r0 = rowptr[i];
            int d = deg[i];
            int r1 = r0 + d;
            float a[4][8];
#pragma unroll
            for (int w = 0; w < 4; ++w)
#pragma unroll
                for (int k = 0; k < 8; ++k) a[w][k] = 0.0f;
            int j = r0;
            for (; j + 8 <= r1; j += 8) {
                uint4 u[8];
#pragma unroll
                for (int m = 0; m < 8; ++m) {
                    int s = csr[j + m];
                    u[m] = *(const uint4*)(hph + (size_t)s * HID + l * 8);
                }
#pragma unroll
                for (int m = 0; m < 8; ++m) {
                    const __half2* p = (const __half2*)&u[m];
#pragma unroll
                    for (int q = 0; q < 4; ++q) {
                        float2 f2 = __half22float2(p[q]);
                        a[m & 3][2 * q]     += f2.x;
                        a[m & 3][2 * q + 1] += f2.y;
                    }
                }
            }
            for (; j + 4 <= r1; j += 4) {
                uint4 u[4];
#pragma unroll
                for (int m = 0; m < 4; ++m) {
                    int s = csr[j + m];
                    u[m] = *(const uint4*)(hph + (size_t)s * HID + l * 8);
                }
#pragma unroll
                for (int m = 0; m < 4; ++m) {
                    const __half2* p = (const __half2*)&u[m];
#pragma unroll
                    for (int q = 0; q < 4; ++q) {
                        float2 f2 = __half22float2(p[q]);
                        a[m][2 * q]     += f2.x;
                        a[m][2 * q + 1] += f2.y;
                    }
                }
            }
            for (; j < r1; ++j) {
                int s = csr[j];
                uint4 u0 = *(const uint4*)(hph + (size_t)s * HID + l * 8);
                const __half2* p = (const __half2*)&u0;
#pragma unroll
                for (int q = 0; q < 4; ++q) {
                    float2 f2 = __half22float2(p[q]);
                    a[0][2 * q]     += f2.x;
                    a[0][2 * q + 1] += f2.y;
                }
            }
            float inv = (d > 0) ? 1.0f / (float)d : 0.0f;
            __half2 o[4];
#pragma unroll
            for (int q = 0; q < 4; ++q) {
                float lo = ((a[0][2*q]   + a[1][2*q])   + (a[2][2*q]   + a[3][2*q]))   * inv;
                float hi = ((a[0][2*q+1] + a[1][2*q+1]) + (a[2][2*q+1] + a[3][2*q+1])) * inv;
                o[q] = __floats2half2_rn(lo, hi);
            }
            *(uint4*)&smean[grp][l * 8] = *(uint4*)o;
        }
    }
    __syncthreads();

    // ---- Phase 2: MFMA on waves 0-1 (16 nodes each) ----
    int wave = t >> 6;
    if (wave >= 2) return;
    int lane = t & 63;
    int m = lane & 15;
    int quad = lane >> 4;
    int node0 = blockIdx.x * 32 + wave * 16;
    if (node0 >= N) return;

    // B fragments (weights, 8 KB each -> L1/L2-resident)
    const _Float16* wlp = (const _Float16*)Wlh;
    const _Float16* wrp = (const _Float16*)Wrh;
    half8 bl[2][4], br[2][4];
#pragma unroll
    for (int kh = 0; kh < 2; ++kh)
#pragma unroll
        for (int nt = 0; nt < 4; ++nt) {
            half8 vl, vr;
#pragma unroll
            for (int j = 0; j < 8; ++j) {
                int k = kh * 32 + quad * 8 + j;
                vl[j] = wlp[k * HID + nt * 16 + m];
                vr[j] = wrp[k * HID + nt * 16 + m];
            }
            bl[kh][nt] = vl;
            br[kh][nt] = vr;
        }

    // A fragments: mean from LDS, hprev from global fp16
    int nlA = wave * 16 + m;
    half8 am0 = *(const half8*)&smean[nlA][quad * 8];
    half8 am1 = *(const half8*)&smean[nlA][32 + quad * 8];
    int nodeA = node0 + m; if (nodeA >= N) nodeA = N - 1;
    const _Float16* hrow = (const _Float16*)hph + (size_t)nodeA * HID;
    half8 ah0 = *(const half8*)(hrow + quad * 8);
    half8 ah1 = *(const half8*)(hrow + 32 + quad * 8);

#pragma unroll
    for (int nt = 0; nt < 4; ++nt) {
        float b = bvec[nt * 16 + m];        // bias depends on col only
        floatx4 c = {b, b, b, b};
        c = __builtin_amdgcn_mfma_f32_16x16x32_f16(am0, bl[0][nt], c, 0, 0, 0);
        c = __builtin_amdgcn_mfma_f32_16x16x32_f16(am1, bl[1][nt], c, 0, 0, 0);
        c = __builtin_amdgcn_mfma_f32_16x16x32_f16(ah0, br[0][nt], c, 0, 0, 0);
        c = __builtin_amdgcn_mfma_f32_16x16x32_f16(ah1, br[1][nt], c, 0, 0, 0);
#pragma unroll
        for (int r = 0; r < 4; ++r) {
            int nodeR = node0 + quad * 4 + r;
            if (nodeR < N) {
                int f = nt * 16 + m;
                float v = c[r];
                v = v > 0.0f ? v : 0.0f;
                float hv = v + hpf[(size_t)nodeR * HID + f];   // exact fp32 residual
                hout[(size_t)nodeR * HID + f] = hv;
                if (houth) houth[(size_t)nodeR * HID + f] = __float2half(hv);
            }
        }
    }
}

// ---------------------------------------------------------------------------
// Global mean pool: batch sorted -> run-length accumulate per wave.
// ---------------------------------------------------------------------------
__global__ __launch_bounds__(256) void pool_kernel(const float* __restrict__ h,
                                                   const void* batch,
                                                   const int* __restrict__ flags,
                                                   float* __restrict__ psum,
                                                   int* __restrict__ gcnt,
                                                   int N, int nodesPerWave) {
    int wave = (blockIdx.x * blockDim.x + threadIdx.x) >> 6;
    int f = threadIdx.x & 63;
    int start = wave * nodesPerWave;
    if (start >= N) return;
    bool is64 = flags[1] != 0;
    int end = start + nodesPerWave;
    if (end > N) end = N;
    int g = idx_at(batch, start, is64);
    float acc = 0.0f;
    int c = 0;
    for (int i = start; i < end; ++i) {
        int gi = idx_at(batch, i, is64);
        if (gi != g) {
            atomicAdd(&psum[g * HID + f], acc);
            if (f == 0) atomicAdd(&gcnt[g], c);
            acc = 0.0f; c = 0; g = gi;
        }
        acc += h[(size_t)i * HID + f];
        c++;
    }
    atomicAdd(&psum[g * HID + f], acc);
    if (f == 0) atomicAdd(&gcnt[g], c);
}

// ---------------------------------------------------------------------------
// FC head: one block (64 threads) per graph.
// ---------------------------------------------------------------------------
__global__ __launch_bounds__(64) void fc_kernel(const float* __restrict__ psum,
                                                const int* __restrict__ gcnt,
                                                const float* __restrict__ Wfc1,
                                                const float* __restrict__ bfc1,
                                                const float* __restrict__ Wfc2,
                                                const float* __restrict__ bfc2,
                                                float* __restrict__ out) {
    int g = blockIdx.x;
    int t = threadIdx.x;
    __shared__ float mean[HID];
    float c = fmaxf((float)gcnt[g], 1.0f);
    mean[t] = psum[g * HID + t] / c;
    __syncthreads();
    float v = 0.0f;
    if (t < 32) {
        float acc = bfc1[t];
#pragma unroll
        for (int k = 0; k < HID; ++k) acc += mean[k] * Wfc1[k * 32 + t];
        float hcc = acc > 0.0f ? acc : 0.0f;
        v = hcc * Wfc2[t];
    }
#pragma unroll
    for (int off = 32; off >= 1; off >>= 1) v += __shfl_down(v, off);
    if (t == 0) out[g] = v + bfc2[0];
}

extern "C" void kernel_launch(void* const* d_in, const int* in_sizes, int n_in,
                              void* d_out, int out_size, void* d_ws, size_t ws_size,
                              hipStream_t stream) {
    const int N = in_sizes[0];       // 50000
    const int E2 = in_sizes[1];      // 2*E
    const int E = E2 / 2;
    const int NB = (N + BUCKET - 1) / BUCKET;   // 782

    const float* x    = (const float*)d_in[0];
    const void*  edge = d_in[1];
    const void*  batch= d_in[2];
    const float* W1l  = (const float*)d_in[3];
    const float* b1   = (const float*)d_in[4];
    const float* W1r  = (const float*)d_in[5];
    const float* W2l  = (const float*)d_in[6];
    const float* b2   = (const float*)d_in[7];
    const float* W2r  = (const float*)d_in[8];
    const float* W3l  = (const float*)d_in[9];
    const float* b3   = (const float*)d_in[10];
    const float* W3r  = (const float*)d_in[11];
    const float* Wfc1 = (const float*)d_in[12];
    const float* bfc1 = (const float*)d_in[13];
    const float* Wfc2 = (const float*)d_in[14];
    const float* bfc2 = (const float*)d_in[15];
    float* out = (float*)d_out;

    // Workspace layout (256 B aligned slices). No host-side memsets.
    char* ws = (char*)d_ws;
    size_t o = 0;
    auto alloc = [&](size_t bytes) { char* p = ws + o; o += (bytes + 255) & ~(size_t)255; return p; };
    int*   bcursor = (int*)alloc((size_t)NB * 4);
    float* psum    = (float*)alloc((size_t)NGRAPHS * HID * 4);
    int*   gcnt    = (int*)alloc((size_t)NGRAPHS * 4);
    unsigned int* entries = (unsigned int*)alloc((size_t)NB * CAP * 4);  // padded
    int*   csr     = (int*)alloc((size_t)NB * CAP * 4);                  // padded
    int*   rowptr  = (int*)alloc((size_t)N * 4);
    int*   deg     = (int*)alloc((size_t)N * 4);
    float* h1      = (float*)alloc((size_t)N * HID * 4);   // reused as h3
    float* h2      = (float*)alloc((size_t)N * HID * 4);
    __half* h1h    = (__half*)alloc((size_t)N * HID * 2);  // fp16 copies
    __half* h2h    = (__half*)alloc((size_t)N * HID * 2);
    __half* wl2h   = (__half*)alloc((size_t)HID * HID * 2);
    __half* wr2h   = (__half*)alloc((size_t)HID * HID * 2);
    __half* wl3h   = (__half*)alloc((size_t)HID * HID * 2);
    __half* wr3h   = (__half*)alloc((size_t)HID * HID * 2);
    int*   flags   = (int*)alloc(16);
    float* h3 = h1;

    // 1. Detect index dtype + init cursors/accumulators + fp16 weight convert
    detect_init_kernel<<<1, 256, 0, stream>>>(edge, batch, flags, bcursor, psum, gcnt,
                                              W2l, W2r, W3l, W3r, wl2h, wr2h, wl3h, wr3h,
                                              E2, N, NGRAPHS, NB);

    // 2. Single-pass binned scatter (LDS-staged edges) into padded regions
    const int nblk = (E + EPB - 1) / EPB;   // 391
    const int scatter_lds = (2 * NB + 2 * EPB) * 4;   // hist+base+ssrc+sdst
    bin_scatter_kernel<<<nblk, 256, scatter_lds, stream>>>(edge, flags, bcursor, entries, E, NB);

    // 3. Fused CSR finalize + layer 1
    csr_l1_kernel<<<NB, 256, 0, stream>>>(entries, bcursor, x, W1l, b1, W1r,
                                          rowptr, deg, csr, h1, h1h, N, NB);

    const int fusedBlocks = (N + 31) / 32;   // 1563 (gather-optimal grid)

    // 4. Layer 2 (fused gather + MFMA transform)
    gather_mfma_kernel<<<fusedBlocks, 256, 0, stream>>>(rowptr, deg, csr, h1h, h1,
                                                        wl2h, b2, wr2h, h2, h2h, N);

    // 5. Layer 3 (fused; no fp16 output copy — nothing gathers from h3)
    gather_mfma_kernel<<<fusedBlocks, 256, 0, stream>>>(rowptr, deg, csr, h2h, h2,
                                                        wl3h, b3, wr3h, h3, (__half*)nullptr, N);

    // 6. Wave-parallel pool (batch sorted -> run-length + atomics)
    {
        int nodesPerWave = 64;
        int waves = (N + nodesPerWave - 1) / nodesPerWave;
        int threads = waves * 64;
        pool_kernel<<<(threads + 255) / 256, 256, 0, stream>>>(h3, batch, flags, psum, gcnt,
                                                               N, nodesPerWave);
    }
    // 7. FC head
    fc_kernel<<<NGRAPHS, 64, 0, stream>>>(psum, gcnt, Wfc1, bfc1, Wfc2, bfc2, out);
}

// Round 17
// 220.976 us; speedup vs baseline: 1.2348x; 1.0907x over previous
//
#include <hip/hip_runtime.h>
#include <hip/hip_bf16.h>
#include <hip/hip_fp16.h>

#define HID 64
#define NGRAPHS 64
#define BUCKET 64        // nodes per bucket (dst >> 6)
#define CAP 4096         // padded entry slots per bucket (mean occupancy ~1024)
#define EPB 2048         // edges per block in bin_scatter (LDS-staged)
#define NSLOT 33         // pool LDS slots (block spans <=32 distinct graphs)

typedef _Float16 half8 __attribute__((ext_vector_type(8)));
typedef float floatx4 __attribute__((ext_vector_type(4)));

// ---------------------------------------------------------------------------
// Detect int64 vs int32, init bucket cursors, zero psum, fp16 weight convert.
// ---------------------------------------------------------------------------
__global__ __launch_bounds__(256) void detect_init_kernel(const void* edge, const void* batch,
                                                          int* flags, int* bcursor,
                                                          float* psum,
                                                          const float* W2l, const float* W2r,
                                                          const float* W3l, const float* W3r,
                                                          __half* wl2h, __half* wr2h,
                                                          __half* wl3h, __half* wr3h,
                                                          int E2, int N, int G, int NB) {
    int t = threadIdx.x;
    for (int i = t; i < NB; i += 256) bcursor[i] = i * CAP;
    for (int i = t; i < G * HID; i += 256) psum[i] = 0.0f;
    for (int i = t; i < HID * HID; i += 256) {
        wl2h[i] = __float2half(W2l[i]);
        wr2h[i] = __float2half(W2r[i]);
        wl3h[i] = __float2half(W3l[i]);
        wr3h[i] = __float2half(W3r[i]);
    }
    if (t < 64) {
        int lane = t;
        int half_ = E2 / 2;
        int stride = half_ / 64; if (stride < 1) stride = 1;
        int j = lane * stride; if (j >= half_) j = half_ - 1;
        long long v = ((const long long*)edge)[j];
        bool ok = (v >= 0 && v < (long long)N);
        unsigned long long m = __ballot(ok);
        if (lane == 0) flags[0] = (m == ~0ULL) ? 1 : 0;
        int halfB = N / 2;
        int strideB = halfB / 64; if (strideB < 1) strideB = 1;
        int jb = lane * strideB; if (jb >= halfB) jb = halfB - 1;
        long long vb = ((const long long*)batch)[jb];
        bool okb = (vb >= 0 && vb < (long long)G);
        unsigned long long mb = __ballot(okb);
        if (lane == 0) flags[1] = (mb == ~0ULL) ? 1 : 0;
    }
}

__device__ __forceinline__ int idx_at(const void* p, int i, bool is64) {
    return is64 ? (int)((const long long*)p)[i] : ((const int*)p)[i];
}

// ---------------------------------------------------------------------------
// Bucket scatter into PADDED per-bucket regions, single global read pass.
// entry = (src << 6) | (dst & 63).
// ---------------------------------------------------------------------------
__global__ __launch_bounds__(256) void bin_scatter_kernel(const void* edge, const int* __restrict__ flags,
                                                          int* __restrict__ bcursor,
                                                          unsigned int* __restrict__ entries,
                                                          int E, int NB) {
    extern __shared__ int lds[];    // hist[NB] + base[NB] + ssrc[EPB] + sdst[EPB]
    int* hist = lds;
    int* base = lds + NB;
    int* ssrc = lds + 2 * NB;
    int* sdst = ssrc + EPB;
    for (int i = threadIdx.x; i < NB; i += 256) hist[i] = 0;
    __syncthreads();
    bool is64 = flags[0] != 0;
    int start = blockIdx.x * EPB;
    int end = start + EPB; if (end > E) end = E;
    int cnt = end - start;
    for (int k = threadIdx.x; k < cnt; k += 256) {
        int e = start + k;
        int srcv = idx_at(edge, e, is64);
        int d = idx_at(edge, E + e, is64);
        ssrc[k] = srcv;
        sdst[k] = d;
        atomicAdd(&hist[d >> 6], 1);
    }
    __syncthreads();
    for (int i = threadIdx.x; i < NB; i += 256) {
        int h = hist[i];
        base[i] = h ? atomicAdd(&bcursor[i], h) : 0;   // absolute position
    }
    __syncthreads();
    for (int i = threadIdx.x; i < NB; i += 256) hist[i] = 0;  // reuse as local cursor
    __syncthreads();
    for (int k = threadIdx.x; k < cnt; k += 256) {
        int d = sdst[k];
        int b = d >> 6;
        int lo = atomicAdd(&hist[b], 1);
        int p = base[b] + lo;
        if (p < (b + 1) * CAP)   // overflow guard (statistically unreachable)
            entries[p] = ((unsigned int)ssrc[k] << 6) | (unsigned int)(d & 63);
    }
}

// ---------------------------------------------------------------------------
// Fused CSR finalize + LAYER 1. Output h1 as fp16 ONLY (all consumers fp16).
// ---------------------------------------------------------------------------
__global__ __launch_bounds__(256) void csr_l1_kernel(const unsigned int* __restrict__ entries,
                                                     const int* __restrict__ bcursor,
                                                     const float* __restrict__ x,
                                                     const float* __restrict__ W1l,
                                                     const float* __restrict__ b1,
                                                     const float* __restrict__ W1r,
                                                     int* __restrict__ rowptr,
                                                     int* __restrict__ deg,
                                                     int* __restrict__ csr,
                                                     __half* __restrict__ h1h,
                                                     int N, int NB) {
    __shared__ int hist[BUCKET];
    __shared__ int lstart[BUCKET];
    __shared__ int lcur[BUCKET];
    __shared__ float accx[BUCKET];
    __shared__ float sx[BUCKET];
    int t = threadIdx.x;
    int b = blockIdx.x;
    int r0 = b * CAP;
    int cnt = bcursor[b] - r0; if (cnt > CAP) cnt = CAP;
    if (t < BUCKET) {
        hist[t] = 0; lcur[t] = 0; accx[t] = 0.0f;
        int node = b * BUCKET + t;
        sx[t] = (node < N) ? x[node] : 0.0f;
    }
    __syncthreads();
    for (int j = r0 + t; j < r0 + cnt; j += 256) {
        unsigned int en = entries[j];
        atomicAdd(&hist[en & 63u], 1);
        atomicAdd(&accx[en & 63u], x[en >> 6]);
    }
    __syncthreads();
    if (t < BUCKET) {  // wave 0: inclusive shuffle scan -> exclusive
        int v = hist[t];
        int s = v;
#pragma unroll
        for (int off = 1; off < 64; off <<= 1) {
            int u = __shfl_up(s, off);
            if (t >= off) s += u;
        }
        lstart[t] = s - v;
        int node = b * BUCKET + t;
        if (node < N) {
            rowptr[node] = r0 + s - v;
            deg[node] = v;
        }
    }
    __syncthreads();
    for (int j = r0 + t; j < r0 + cnt; j += 256) {
        unsigned int en = entries[j];
        int dl = (int)(en & 63u);
        int p = atomicAdd(&lcur[dl], 1);
        csr[r0 + lstart[dl] + p] = (int)(en >> 6);
    }
    __syncthreads();
    // Layer-1 transform: 4 subs x 64 features
    int f = t & 63;
    int sub = t >> 6;
    float wlf = W1l[f], bf = b1[f], wrf = W1r[f];
    for (int it = 0; it < 16; ++it) {
        int nl = it * 4 + sub;
        int node = b * BUCKET + nl;
        if (node < N) {
            int d = hist[nl];
            float mv = (d > 0) ? accx[nl] / (float)d : 0.0f;
            float xv = sx[nl];
            float v = fmaf(mv, wlf, fmaf(xv, wrf, bf));
            v = v > 0.0f ? v : 0.0f;
            h1h[(size_t)node * HID + f] = __float2half(v + xv);
        }
    }
}

// ---------------------------------------------------------------------------
// FUSED gather + MFMA node transform (+ optional pool epilogue).
// 32 nodes per 256-thread block.
// Phase 1: 8 lanes/node gather fp16 neighbor rows -> fp16 mean in LDS.
// Phase 2 (waves 0-1): D = Mean·Wl + Hp·Wr + b (fp32 acc), relu, fp16
//   residual. If psum != null (layer 3): pool into LDS per-graph tile and
//   flush with atomics (h3 is never materialized). Else: write fp16 hout.
// MFMA layouts per learn_hip m89/m91.
// ---------------------------------------------------------------------------
__global__ __launch_bounds__(256) void gather_mfma_kernel(const int* __restrict__ rowptr,
                                                          const int* __restrict__ deg,
                                                          const int* __restrict__ csr,
                                                          const __half* __restrict__ hph,
                                                          const __half* __restrict__ Wlh,
                                                          const float* __restrict__ bvec,
                                                          const __half* __restrict__ Wrh,
                                                          __half* __restrict__ houth,
                                                          float* __restrict__ psum,
                                                          const void* batch,
                                                          const int* __restrict__ flags,
                                                          int N) {
    __shared__ _Float16 smean[32][HID + 8];   // padded rows, 16B-aligned
    __shared__ float spool[NSLOT][HID];
    __shared__ int sb[32];
    int t = threadIdx.x;
    bool pool = (psum != nullptr);
    if (pool) {
        for (int i = t; i < NSLOT * HID; i += 256) ((float*)spool)[i] = 0.0f;
        if (t < 32) {
            int node = blockIdx.x * 32 + t;
            sb[t] = (node < N) ? idx_at(batch, node, flags[1] != 0) : -1;
        }
    }

    // ---- Phase 1: gather means (8 lanes/node x 32 nodes) ----
    {
        int grp = t >> 3;
        int l = t & 7;
        int i = blockIdx.x * 32 + grp;
        if (i < N) {
            int r0 = rowptr[i];
            int d = deg[i];
            int r1 = r0 + d;
            float a[4][8];
#pragma unroll
            for (int w = 0; w < 4; ++w)
#pragma unroll
                for (int k = 0; k < 8; ++k) a[w][k] = 0.0f;
            int j = r0;
            for (; j + 8 <= r1; j += 8) {
                uint4 u[8];
#pragma unroll
                for (int m = 0; m < 8; ++m) {
                    int s = csr[j + m];
                    u[m] = *(const uint4*)(hph + (size_t)s * HID + l * 8);
                }
#pragma unroll
                for (int m = 0; m < 8; ++m) {
                    const __half2* p = (const __half2*)&u[m];
#pragma unroll
                    for (int q = 0; q < 4; ++q) {
                        float2 f2 = __half22float2(p[q]);
                        a[m & 3][2 * q]     += f2.x;
                        a[m & 3][2 * q + 1] += f2.y;
                    }
                }
            }
            for (; j + 4 <= r1; j += 4) {
                uint4 u[4];
#pragma unroll
                for (int m = 0; m < 4; ++m) {
                    int s = csr[j + m];
                    u[m] = *(const uint4*)(hph + (size_t)s * HID + l * 8);
                }
#pragma unroll
                for (int m = 0; m < 4; ++m) {
                    const __half2* p = (const __half2*)&u[m];
#pragma unroll
                    for (int q = 0; q < 4; ++q) {
                        float2 f2 = __half22float2(p[q]);
                        a[m][2 * q]     += f2.x;
                        a[m][2 * q + 1] += f2.y;
                    }
                }
            }
            for (; j < r1; ++j) {
                int s = csr[j];
                uint4 u0 = *(const uint4*)(hph + (size_t)s * HID + l * 8);
                const __half2* p = (const __half2*)&u0;
#pragma unroll
                for (int q = 0; q < 4; ++q) {
                    float2 f2 = __half22float2(p[q]);
                    a[0][2 * q]     += f2.x;
                    a[0][2 * q + 1] += f2.y;
                }
            }
            float inv = (d > 0) ? 1.0f / (float)d : 0.0f;
            __half2 o[4];
#pragma unroll
            for (int q = 0; q < 4; ++q) {
                float lo = ((a[0][2*q]   + a[1][2*q])   + (a[2][2*q]   + a[3][2*q]))   * inv;
                float hi = ((a[0][2*q+1] + a[1][2*q+1]) + (a[2][2*q+1] + a[3][2*q+1])) * inv;
                o[q] = __floats2half2_rn(lo, hi);
            }
            *(uint4*)&smean[grp][l * 8] = *(uint4*)o;
        }
    }
    __syncthreads();

    // ---- Phase 2: MFMA on waves 0-1 (16 nodes each) ----
    int wave = t >> 6;
    int lane = t & 63;
    int m = lane & 15;
    int quad = lane >> 4;
    int node0 = blockIdx.x * 32 + wave * 16;
    if (wave < 2 && node0 < N) {
        const _Float16* wlp = (const _Float16*)Wlh;
        const _Float16* wrp = (const _Float16*)Wrh;
        half8 bl[2][4], br[2][4];
#pragma unroll
        for (int kh = 0; kh < 2; ++kh)
#pragma unroll
            for (int nt = 0; nt < 4; ++nt) {
                half8 vl, vr;
#pragma unroll
                for (int j = 0; j < 8; ++j) {
                    int k = kh * 32 + quad * 8 + j;
                    vl[j] = wlp[k * HID + nt * 16 + m];
                    vr[j] = wrp[k * HID + nt * 16 + m];
                }
                bl[kh][nt] = vl;
                br[kh][nt] = vr;
            }
        int nlA = wave * 16 + m;
        half8 am0 = *(const half8*)&smean[nlA][quad * 8];
        half8 am1 = *(const half8*)&smean[nlA][32 + quad * 8];
        int nodeA = node0 + m; if (nodeA >= N) nodeA = N - 1;
        const _Float16* hrow = (const _Float16*)hph + (size_t)nodeA * HID;
        half8 ah0 = *(const half8*)(hrow + quad * 8);
        half8 ah1 = *(const half8*)(hrow + 32 + quad * 8);

#pragma unroll
        for (int nt = 0; nt < 4; ++nt) {
            float b = bvec[nt * 16 + m];
            floatx4 c = {b, b, b, b};
            c = __builtin_amdgcn_mfma_f32_16x16x32_f16(am0, bl[0][nt], c, 0, 0, 0);
            c = __builtin_amdgcn_mfma_f32_16x16x32_f16(am1, bl[1][nt], c, 0, 0, 0);
            c = __builtin_amdgcn_mfma_f32_16x16x32_f16(ah0, br[0][nt], c, 0, 0, 0);
            c = __builtin_amdgcn_mfma_f32_16x16x32_f16(ah1, br[1][nt], c, 0, 0, 0);
            int f = nt * 16 + m;
#pragma unroll
            for (int r = 0; r < 4; ++r) {
                int nodeR = node0 + quad * 4 + r;
                if (nodeR < N) {
                    float v = c[r];
                    v = v > 0.0f ? v : 0.0f;
                    // residual from fp16 hprev (L1-hot: rows loaded as A-frags)
                    v += __half2float(((const __half*)hph)[(size_t)nodeR * HID + f]);
                    if (!pool) {
                        houth[(size_t)nodeR * HID + f] = __float2half(v);
                    } else {
                        int bg = sb[wave * 16 + quad * 4 + r];
                        int slot = bg - sb[0];
                        if (slot < NSLOT) atomicAdd(&spool[slot][f], v);
                        else atomicAdd(&psum[bg * HID + f], v);
                    }
                }
            }
        }
    }

    if (pool) {
        __syncthreads();
        int gbase = sb[0];
        for (int i = t; i < NSLOT * HID; i += 256) {
            int s = i >> 6, f = i & 63;
            float v = spool[s][f];
            if (v != 0.0f) atomicAdd(&psum[(gbase + s) * HID + f], v);
        }
    }
}

// ---------------------------------------------------------------------------
// FC head: one block (64 threads) per graph. Graph node-count via binary
// search in the sorted batch array (no gcnt buffer).
// ---------------------------------------------------------------------------
__device__ __forceinline__ int lbound(const void* batch, int n, long long key, bool is64) {
    int lo = 0, hi = n;
    while (lo < hi) {
        int mid = (lo + hi) >> 1;
        long long v = is64 ? ((const long long*)batch)[mid] : (long long)((const int*)batch)[mid];
        if (v < key) lo = mid + 1; else hi = mid;
    }
    return lo;
}

__global__ __launch_bounds__(64) void fc_kernel(const float* __restrict__ psum,
                                                const void* batch,
                                                const int* __restrict__ flags,
                                                const float* __restrict__ Wfc1,
                                                const float* __restrict__ bfc1,
                                                const float* __restrict__ Wfc2,
                                                const float* __restrict__ bfc2,
                                                float* __restrict__ out, int N) {
    __shared__ int sb2[2];
    __shared__ float mean[HID];
    int g = blockIdx.x;
    int t = threadIdx.x;
    bool is64 = flags[1] != 0;
    if (t == 0) sb2[0] = lbound(batch, N, g, is64);
    if (t == 1) sb2[1] = lbound(batch, N, g + 1, is64);
    __syncthreads();
    float c = fmaxf((float)(sb2[1] - sb2[0]), 1.0f);
    mean[t] = psum[g * HID + t] / c;
    __syncthreads();
    float v = 0.0f;
    if (t < 32) {
        float acc = bfc1[t];
#pragma unroll
        for (int k = 0; k < HID; ++k) acc += mean[k] * Wfc1[k * 32 + t];
        float hcc = acc > 0.0f ? acc : 0.0f;
        v = hcc * Wfc2[t];
    }
#pragma unroll
    for (int off = 32; off >= 1; off >>= 1) v += __shfl_down(v, off);
    if (t == 0) out[g] = v + bfc2[0];
}

extern "C" void kernel_launch(void* const* d_in, const int* in_sizes, int n_in,
                              void* d_out, int out_size, void* d_ws, size_t ws_size,
                              hipStream_t stream) {
    const int N = in_sizes[0];       // 50000
    const int E2 = in_sizes[1];      // 2*E
    const int E = E2 / 2;
    const int NB = (N + BUCKET - 1) / BUCKET;   // 782

    const float* x    = (const float*)d_in[0];
    const void*  edge = d_in[1];
    const void*  batch= d_in[2];
    const float* W1l  = (const float*)d_in[3];
    const float* b1   = (const float*)d_in[4];
    const float* W1r  = (const float*)d_in[5];
    const float* W2l  = (const float*)d_in[6];
    const float* b2   = (const float*)d_in[7];
    const float* W2r  = (const float*)d_in[8];
    const float* W3l  = (const float*)d_in[9];
    const float* b3   = (const float*)d_in[10];
    const float* W3r  = (const float*)d_in[11];
    const float* Wfc1 = (const float*)d_in[12];
    const float* bfc1 = (const float*)d_in[13];
    const float* Wfc2 = (const float*)d_in[14];
    const float* bfc2 = (const float*)d_in[15];
    float* out = (float*)d_out;

    // Workspace layout (256 B aligned slices). No host-side memsets.
    char* ws = (char*)d_ws;
    size_t o = 0;
    auto alloc = [&](size_t bytes) { char* p = ws + o; o += (bytes + 255) & ~(size_t)255; return p; };
    int*   bcursor = (int*)alloc((size_t)NB * 4);
    float* psum    = (float*)alloc((size_t)NGRAPHS * HID * 4);
    unsigned int* entries = (unsigned int*)alloc((size_t)NB * CAP * 4);  // padded
    int*   csr     = (int*)alloc((size_t)NB * CAP * 4);                  // padded
    int*   rowptr  = (int*)alloc((size_t)N * 4);
    int*   deg     = (int*)alloc((size_t)N * 4);
    __half* h1h    = (__half*)alloc((size_t)N * HID * 2);  // fp16 activations
    __half* h2h    = (__half*)alloc((size_t)N * HID * 2);
    __half* wl2h   = (__half*)alloc((size_t)HID * HID * 2);
    __half* wr2h   = (__half*)alloc((size_t)HID * HID * 2);
    __half* wl3h   = (__half*)alloc((size_t)HID * HID * 2);
    __half* wr3h   = (__half*)alloc((size_t)HID * HID * 2);
    int*   flags   = (int*)alloc(16);

    // 1. Detect index dtype + init cursors + zero psum + fp16 weight convert
    detect_init_kernel<<<1, 256, 0, stream>>>(edge, batch, flags, bcursor, psum,
                                              W2l, W2r, W3l, W3r, wl2h, wr2h, wl3h, wr3h,
                                              E2, N, NGRAPHS, NB);

    // 2. Single-pass binned scatter (LDS-staged edges) into padded regions
    const int nblk = (E + EPB - 1) / EPB;   // 391
    const int scatter_lds = (2 * NB + 2 * EPB) * 4;
    bin_scatter_kernel<<<nblk, 256, scatter_lds, stream>>>(edge, flags, bcursor, entries, E, NB);

    // 3. Fused CSR finalize + layer 1 (fp16 h1 only)
    csr_l1_kernel<<<NB, 256, 0, stream>>>(entries, bcursor, x, W1l, b1, W1r,
                                          rowptr, deg, csr, h1h, N, NB);

    const int fusedBlocks = (N + 31) / 32;   // 1563

    // 4. Layer 2 (fused gather + MFMA; writes fp16 h2 only)
    gather_mfma_kernel<<<fusedBlocks, 256, 0, stream>>>(rowptr, deg, csr, h1h,
                                                        wl2h, b2, wr2h, h2h,
                                                        (float*)nullptr, nullptr, flags, N);

    // 5. Layer 3 (fused gather + MFMA + POOL epilogue; h3 never materialized)
    gather_mfma_kernel<<<fusedBlocks, 256, 0, stream>>>(rowptr, deg, csr, h2h,
                                                        wl3h, b3, wr3h, (__half*)nullptr,
                                                        psum, batch, flags, N);

    // 6. FC head (graph bounds via binary search in sorted batch)
    fc_kernel<<<NGRAPHS, 64, 0, stream>>>(psum, batch, flags, Wfc1, bfc1, Wfc2, bfc2, out, N);
}

// Round 18
// 209.189 us; speedup vs baseline: 1.3044x; 1.0563x over previous
//
#include <hip/hip_runtime.h>
#include <hip/hip_bf16.h>
#include <hip/hip_fp16.h>

#define HID 64
#define NGRAPHS 64
#define BUCKET 64        // nodes per bucket (dst >> 6)
#define CAP 4096         // padded entry slots per bucket (mean occupancy ~1024)
#define EPB 2048         // edges per block in bin_scatter (LDS-staged)
#define NSLOT 33         // pool LDS slots (block spans <=32 distinct graphs)

typedef _Float16 half8 __attribute__((ext_vector_type(8)));
typedef float floatx4 __attribute__((ext_vector_type(4)));
typedef float floatx2 __attribute__((ext_vector_type(2)));

__device__ __forceinline__ unsigned char enc_fp8(float v) {
    // OCP e4m3 encode via HW pack (gfx950): low byte of packed pair
    int pk = __builtin_amdgcn_cvt_pk_fp8_f32(v, v, 0, false);
    return (unsigned char)(pk & 0xff);
}

// ---------------------------------------------------------------------------
// Detect int64 vs int32, init bucket cursors, zero psum, fp16 weight convert.
// 5 blocks: block 0 = flags+cursors+psum; blocks 1-4 = one weight matrix each.
// ---------------------------------------------------------------------------
__global__ __launch_bounds__(256) void detect_init_kernel(const void* edge, const void* batch,
                                                          int* flags, int* bcursor,
                                                          float* psum,
                                                          const float* W2l, const float* W2r,
                                                          const float* W3l, const float* W3r,
                                                          __half* wl2h, __half* wr2h,
                                                          __half* wl3h, __half* wr3h,
                                                          int E2, int N, int G, int NB) {
    int t = threadIdx.x;
    int b = blockIdx.x;
    if (b == 0) {
        for (int i = t; i < NB; i += 256) bcursor[i] = i * CAP;
        for (int i = t; i < G * HID; i += 256) psum[i] = 0.0f;
        if (t < 64) {
            int lane = t;
            int half_ = E2 / 2;
            int stride = half_ / 64; if (stride < 1) stride = 1;
            int j = lane * stride; if (j >= half_) j = half_ - 1;
            long long v = ((const long long*)edge)[j];
            bool ok = (v >= 0 && v < (long long)N);
            unsigned long long m = __ballot(ok);
            if (lane == 0) flags[0] = (m == ~0ULL) ? 1 : 0;
            int halfB = N / 2;
            int strideB = halfB / 64; if (strideB < 1) strideB = 1;
            int jb = lane * strideB; if (jb >= halfB) jb = halfB - 1;
            long long vb = ((const long long*)batch)[jb];
            bool okb = (vb >= 0 && vb < (long long)G);
            unsigned long long mb = __ballot(okb);
            if (lane == 0) flags[1] = (mb == ~0ULL) ? 1 : 0;
        }
    } else {
        const float* src = (b == 1) ? W2l : (b == 2) ? W2r : (b == 3) ? W3l : W3r;
        __half* dst = (b == 1) ? wl2h : (b == 2) ? wr2h : (b == 3) ? wl3h : wr3h;
        for (int i = t; i < HID * HID; i += 256) dst[i] = __float2half(src[i]);
    }
}

__device__ __forceinline__ int idx_at(const void* p, int i, bool is64) {
    return is64 ? (int)((const long long*)p)[i] : ((const int*)p)[i];
}

// ---------------------------------------------------------------------------
// Bucket scatter into PADDED per-bucket regions, single global read pass.
// entry = (src << 6) | (dst & 63).
// ---------------------------------------------------------------------------
__global__ __launch_bounds__(256) void bin_scatter_kernel(const void* edge, const int* __restrict__ flags,
                                                          int* __restrict__ bcursor,
                                                          unsigned int* __restrict__ entries,
                                                          int E, int NB) {
    extern __shared__ int lds[];    // hist[NB] + base[NB] + ssrc[EPB] + sdst[EPB]
    int* hist = lds;
    int* base = lds + NB;
    int* ssrc = lds + 2 * NB;
    int* sdst = ssrc + EPB;
    for (int i = threadIdx.x; i < NB; i += 256) hist[i] = 0;
    __syncthreads();
    bool is64 = flags[0] != 0;
    int start = blockIdx.x * EPB;
    int end = start + EPB; if (end > E) end = E;
    int cnt = end - start;
    for (int k = threadIdx.x; k < cnt; k += 256) {
        int e = start + k;
        int srcv = idx_at(edge, e, is64);
        int d = idx_at(edge, E + e, is64);
        ssrc[k] = srcv;
        sdst[k] = d;
        atomicAdd(&hist[d >> 6], 1);
    }
    __syncthreads();
    for (int i = threadIdx.x; i < NB; i += 256) {
        int h = hist[i];
        base[i] = h ? atomicAdd(&bcursor[i], h) : 0;   // absolute position
    }
    __syncthreads();
    for (int i = threadIdx.x; i < NB; i += 256) hist[i] = 0;  // reuse as local cursor
    __syncthreads();
    for (int k = threadIdx.x; k < cnt; k += 256) {
        int d = sdst[k];
        int b = d >> 6;
        int lo = atomicAdd(&hist[b], 1);
        int p = base[b] + lo;
        if (p < (b + 1) * CAP)   // overflow guard (statistically unreachable)
            entries[p] = ((unsigned int)ssrc[k] << 6) | (unsigned int)(d & 63);
    }
}

// ---------------------------------------------------------------------------
// Fused CSR finalize + LAYER 1. Outputs h1 as fp16 (Hp path/residual) AND
// fp8 e4m3 (next layer's gather: 64 B rows, L2-resident working set).
// ---------------------------------------------------------------------------
__global__ __launch_bounds__(256) void csr_l1_kernel(const unsigned int* __restrict__ entries,
                                                     const int* __restrict__ bcursor,
                                                     const float* __restrict__ x,
                                                     const float* __restrict__ W1l,
                                                     const float* __restrict__ b1,
                                                     const float* __restrict__ W1r,
                                                     int* __restrict__ rowptr,
                                                     int* __restrict__ deg,
                                                     int* __restrict__ csr,
                                                     __half* __restrict__ h1h,
                                                     unsigned char* __restrict__ h1q,
                                                     int N, int NB) {
    __shared__ int hist[BUCKET];
    __shared__ int lstart[BUCKET];
    __shared__ int lcur[BUCKET];
    __shared__ float accx[BUCKET];
    __shared__ float sx[BUCKET];
    int t = threadIdx.x;
    int b = blockIdx.x;
    int r0 = b * CAP;
    int cnt = bcursor[b] - r0; if (cnt > CAP) cnt = CAP;
    if (t < BUCKET) {
        hist[t] = 0; lcur[t] = 0; accx[t] = 0.0f;
        int node = b * BUCKET + t;
        sx[t] = (node < N) ? x[node] : 0.0f;
    }
    __syncthreads();
    for (int j = r0 + t; j < r0 + cnt; j += 256) {
        unsigned int en = entries[j];
        atomicAdd(&hist[en & 63u], 1);
        atomicAdd(&accx[en & 63u], x[en >> 6]);
    }
    __syncthreads();
    if (t < BUCKET) {  // wave 0: inclusive shuffle scan -> exclusive
        int v = hist[t];
        int s = v;
#pragma unroll
        for (int off = 1; off < 64; off <<= 1) {
            int u = __shfl_up(s, off);
            if (t >= off) s += u;
        }
        lstart[t] = s - v;
        int node = b * BUCKET + t;
        if (node < N) {
            rowptr[node] = r0 + s - v;
            deg[node] = v;
        }
    }
    __syncthreads();
    for (int j = r0 + t; j < r0 + cnt; j += 256) {
        unsigned int en = entries[j];
        int dl = (int)(en & 63u);
        int p = atomicAdd(&lcur[dl], 1);
        csr[r0 + lstart[dl] + p] = (int)(en >> 6);
    }
    __syncthreads();
    // Layer-1 transform: 4 subs x 64 features
    int f = t & 63;
    int sub = t >> 6;
    float wlf = W1l[f], bf = b1[f], wrf = W1r[f];
    for (int it = 0; it < 16; ++it) {
        int nl = it * 4 + sub;
        int node = b * BUCKET + nl;
        if (node < N) {
            int d = hist[nl];
            float mv = (d > 0) ? accx[nl] / (float)d : 0.0f;
            float xv = sx[nl];
            float v = fmaf(mv, wlf, fmaf(xv, wrf, bf));
            v = v > 0.0f ? v : 0.0f;
            float hv = v + xv;
            h1h[(size_t)node * HID + f] = __float2half(hv);
            h1q[(size_t)node * HID + f] = enc_fp8(hv);
        }
    }
}

// ---------------------------------------------------------------------------
// FUSED gather + MFMA node transform (+ optional pool epilogue).
// Phase 1: 8 lanes/node gather FP8 neighbor rows (64 B = 1 line/edge,
//   3.2 MB working set -> per-XCD L2 resident) -> fp32 acc -> fp16 mean LDS.
// Phase 2 (waves 0-1): D = Mean·Wl + Hp(fp16)·Wr + b, relu, fp16 residual.
//   Layer 3 (psum != null): pool into LDS tile, flush atomics; else write
//   fp16 + fp8 hout. MFMA layouts per learn_hip m89/m91.
// ---------------------------------------------------------------------------
__global__ __launch_bounds__(256) void gather_mfma_kernel(const int* __restrict__ rowptr,
                                                          const int* __restrict__ deg,
                                                          const int* __restrict__ csr,
                                                          const unsigned char* __restrict__ hq,
                                                          const __half* __restrict__ hph,
                                                          const __half* __restrict__ Wlh,
                                                          const float* __restrict__ bvec,
                                                          const __half* __restrict__ Wrh,
                                                          __half* __restrict__ houth,
                                                          unsigned char* __restrict__ houtq,
                                                          float* __restrict__ psum,
                                                          const void* batch,
                                                          const int* __restrict__ flags,
                                                          int N) {
    __shared__ _Float16 smean[32][HID + 8];   // padded rows, 16B-aligned
    __shared__ float spool[NSLOT][HID];
    __shared__ int sb[32];
    int t = threadIdx.x;
    bool pool = (psum != nullptr);
    if (pool) {
        for (int i = t; i < NSLOT * HID; i += 256) ((float*)spool)[i] = 0.0f;
        if (t < 32) {
            int node = blockIdx.x * 32 + t;
            sb[t] = (node < N) ? idx_at(batch, node, flags[1] != 0) : -1;
        }
    }

    // ---- Phase 1: gather means from FP8 rows (8 lanes/node x 32 nodes) ----
    {
        int grp = t >> 3;
        int l = t & 7;           // 8 features x 8 fp8 per lane (8 B)
        int i = blockIdx.x * 32 + grp;
        if (i < N) {
            int r0 = rowptr[i];
            int d = deg[i];
            int r1 = r0 + d;
            float a[4][8];
#pragma unroll
            for (int w = 0; w < 4; ++w)
#pragma unroll
                for (int k = 0; k < 8; ++k) a[w][k] = 0.0f;
            int j = r0;
            for (; j + 8 <= r1; j += 8) {
                uint2 u[8];
#pragma unroll
                for (int m = 0; m < 8; ++m) {
                    int s = csr[j + m];
                    u[m] = *(const uint2*)(hq + (size_t)s * HID + l * 8);
                }
#pragma unroll
                for (int m = 0; m < 8; ++m) {
                    floatx2 p0 = __builtin_amdgcn_cvt_pk_f32_fp8(u[m].x, false);
                    floatx2 p1 = __builtin_amdgcn_cvt_pk_f32_fp8(u[m].x, true);
                    floatx2 p2 = __builtin_amdgcn_cvt_pk_f32_fp8(u[m].y, false);
                    floatx2 p3 = __builtin_amdgcn_cvt_pk_f32_fp8(u[m].y, true);
                    int w = m & 3;
                    a[w][0] += p0[0]; a[w][1] += p0[1];
                    a[w][2] += p1[0]; a[w][3] += p1[1];
                    a[w][4] += p2[0]; a[w][5] += p2[1];
                    a[w][6] += p3[0]; a[w][7] += p3[1];
                }
            }
            for (; j < r1; ++j) {
                int s = csr[j];
                uint2 u0 = *(const uint2*)(hq + (size_t)s * HID + l * 8);
                floatx2 p0 = __builtin_amdgcn_cvt_pk_f32_fp8(u0.x, false);
                floatx2 p1 = __builtin_amdgcn_cvt_pk_f32_fp8(u0.x, true);
                floatx2 p2 = __builtin_amdgcn_cvt_pk_f32_fp8(u0.y, false);
                floatx2 p3 = __builtin_amdgcn_cvt_pk_f32_fp8(u0.y, true);
                a[0][0] += p0[0]; a[0][1] += p0[1];
                a[0][2] += p1[0]; a[0][3] += p1[1];
                a[0][4] += p2[0]; a[0][5] += p2[1];
                a[0][6] += p3[0]; a[0][7] += p3[1];
            }
            float inv = (d > 0) ? 1.0f / (float)d : 0.0f;
            __half2 o[4];
#pragma unroll
            for (int q = 0; q < 4; ++q) {
                float lo = ((a[0][2*q]   + a[1][2*q])   + (a[2][2*q]   + a[3][2*q]))   * inv;
                float hi = ((a[0][2*q+1] + a[1][2*q+1]) + (a[2][2*q+1] + a[3][2*q+1])) * inv;
                o[q] = __floats2half2_rn(lo, hi);
            }
            *(uint4*)&smean[grp][l * 8] = *(uint4*)o;
        }
    }
    __syncthreads();

    // ---- Phase 2: MFMA on waves 0-1 (16 nodes each) ----
    int wave = t >> 6;
    int lane = t & 63;
    int m = lane & 15;
    int quad = lane >> 4;
    int node0 = blockIdx.x * 32 + wave * 16;
    if (wave < 2 && node0 < N) {
        const _Float16* wlp = (const _Float16*)Wlh;
        const _Float16* wrp = (const _Float16*)Wrh;
        half8 bl[2][4], br[2][4];
#pragma unroll
        for (int kh = 0; kh < 2; ++kh)
#pragma unroll
            for (int nt = 0; nt < 4; ++nt) {
                half8 vl, vr;
#pragma unroll
                for (int j = 0; j < 8; ++j) {
                    int k = kh * 32 + quad * 8 + j;
                    vl[j] = wlp[k * HID + nt * 16 + m];
                    vr[j] = wrp[k * HID + nt * 16 + m];
                }
                bl[kh][nt] = vl;
                br[kh][nt] = vr;
            }
        int nlA = wave * 16 + m;
        half8 am0 = *(const half8*)&smean[nlA][quad * 8];
        half8 am1 = *(const half8*)&smean[nlA][32 + quad * 8];
        int nodeA = node0 + m; if (nodeA >= N) nodeA = N - 1;
        const _Float16* hrow = (const _Float16*)hph + (size_t)nodeA * HID;
        half8 ah0 = *(const half8*)(hrow + quad * 8);
        half8 ah1 = *(const half8*)(hrow + 32 + quad * 8);

#pragma unroll
        for (int nt = 0; nt < 4; ++nt) {
            float b = bvec[nt * 16 + m];
            floatx4 c = {b, b, b, b};
            c = __builtin_amdgcn_mfma_f32_16x16x32_f16(am0, bl[0][nt], c, 0, 0, 0);
            c = __builtin_amdgcn_mfma_f32_16x16x32_f16(am1, bl[1][nt], c, 0, 0, 0);
            c = __builtin_amdgcn_mfma_f32_16x16x32_f16(ah0, br[0][nt], c, 0, 0, 0);
            c = __builtin_amdgcn_mfma_f32_16x16x32_f16(ah1, br[1][nt], c, 0, 0, 0);
            int f = nt * 16 + m;
#pragma unroll
            for (int r = 0; r < 4; ++r) {
                int nodeR = node0 + quad * 4 + r;
                if (nodeR < N) {
                    float v = c[r];
                    v = v > 0.0f ? v : 0.0f;
                    v += __half2float(((const __half*)hph)[(size_t)nodeR * HID + f]);
                    if (!pool) {
                        houth[(size_t)nodeR * HID + f] = __float2half(v);
                        houtq[(size_t)nodeR * HID + f] = enc_fp8(v);
                    } else {
                        int bg = sb[wave * 16 + quad * 4 + r];
                        int slot = bg - sb[0];
                        if (slot < NSLOT) atomicAdd(&spool[slot][f], v);
                        else atomicAdd(&psum[bg * HID + f], v);
                    }
                }
            }
        }
    }

    if (pool) {
        __syncthreads();
        int gbase = sb[0];
        for (int i = t; i < NSLOT * HID; i += 256) {
            int s = i >> 6, f = i & 63;
            float v = spool[s][f];
            if (v != 0.0f) atomicAdd(&psum[(gbase + s) * HID + f], v);
        }
    }
}

// ---------------------------------------------------------------------------
// FC head: one block (64 threads) per graph. Graph node-count via binary
// search in the sorted batch array.
// ---------------------------------------------------------------------------
__device__ __forceinline__ int lbound(const void* batch, int n, long long key, bool is64) {
    int lo = 0, hi = n;
    while (lo < hi) {
        int mid = (lo + hi) >> 1;
        long long v = is64 ? ((const long long*)batch)[mid] : (long long)((const int*)batch)[mid];
        if (v < key) lo = mid + 1; else hi = mid;
    }
    return lo;
}

__global__ __launch_bounds__(64) void fc_kernel(const float* __restrict__ psum,
                                                const void* batch,
                                                const int* __restrict__ flags,
                                                const float* __restrict__ Wfc1,
                                                const float* __restrict__ bfc1,
                                                const float* __restrict__ Wfc2,
                                                const float* __restrict__ bfc2,
                                                float* __restrict__ out, int N) {
    __shared__ int sb2[2];
    __shared__ float mean[HID];
    int g = blockIdx.x;
    int t = threadIdx.x;
    bool is64 = flags[1] != 0;
    if (t == 0) sb2[0] = lbound(batch, N, g, is64);
    if (t == 1) sb2[1] = lbound(batch, N, g + 1, is64);
    __syncthreads();
    float c = fmaxf((float)(sb2[1] - sb2[0]), 1.0f);
    mean[t] = psum[g * HID + t] / c;
    __syncthreads();
    float v = 0.0f;
    if (t < 32) {
        float acc = bfc1[t];
#pragma unroll
        for (int k = 0; k < HID; ++k) acc += mean[k] * Wfc1[k * 32 + t];
        float hcc = acc > 0.0f ? acc : 0.0f;
        v = hcc * Wfc2[t];
    }
#pragma unroll
    for (int off = 32; off >= 1; off >>= 1) v += __shfl_down(v, off);
    if (t == 0) out[g] = v + bfc2[0];
}

extern "C" void kernel_launch(void* const* d_in, const int* in_sizes, int n_in,
                              void* d_out, int out_size, void* d_ws, size_t ws_size,
                              hipStream_t stream) {
    const int N = in_sizes[0];       // 50000
    const int E2 = in_sizes[1];      // 2*E
    const int E = E2 / 2;
    const int NB = (N + BUCKET - 1) / BUCKET;   // 782

    const float* x    = (const float*)d_in[0];
    const void*  edge = d_in[1];
    const void*  batch= d_in[2];
    const float* W1l  = (const float*)d_in[3];
    const float* b1   = (const float*)d_in[4];
    const float* W1r  = (const float*)d_in[5];
    const float* W2l  = (const float*)d_in[6];
    const float* b2   = (const float*)d_in[7];
    const float* W2r  = (const float*)d_in[8];
    const float* W3l  = (const float*)d_in[9];
    const float* b3   = (const float*)d_in[10];
    const float* W3r  = (const float*)d_in[11];
    const float* Wfc1 = (const float*)d_in[12];
    const float* bfc1 = (const float*)d_in[13];
    const float* Wfc2 = (const float*)d_in[14];
    const float* bfc2 = (const float*)d_in[15];
    float* out = (float*)d_out;

    // Workspace layout (256 B aligned slices). No host-side memsets.
    char* ws = (char*)d_ws;
    size_t o = 0;
    auto alloc = [&](size_t bytes) { char* p = ws + o; o += (bytes + 255) & ~(size_t)255; return p; };
    int*   bcursor = (int*)alloc((size_t)NB * 4);
    float* psum    = (float*)alloc((size_t)NGRAPHS * HID * 4);
    unsigned int* entries = (unsigned int*)alloc((size_t)NB * CAP * 4);  // padded
    int*   csr     = (int*)alloc((size_t)NB * CAP * 4);                  // padded
    int*   rowptr  = (int*)alloc((size_t)N * 4);
    int*   deg     = (int*)alloc((size_t)N * 4);
    __half* h1h    = (__half*)alloc((size_t)N * HID * 2);  // fp16 activations
    __half* h2h    = (__half*)alloc((size_t)N * HID * 2);
    unsigned char* h1q = (unsigned char*)alloc((size_t)N * HID);  // fp8 gather copies
    unsigned char* h2q = (unsigned char*)alloc((size_t)N * HID);
    __half* wl2h   = (__half*)alloc((size_t)HID * HID * 2);
    __half* wr2h   = (__half*)alloc((size_t)HID * HID * 2);
    __half* wl3h   = (__half*)alloc((size_t)HID * HID * 2);
    __half* wr3h   = (__half*)alloc((size_t)HID * HID * 2);
    int*   flags   = (int*)alloc(16);

    // 1. Detect + init + weight convert (parallelized across 5 blocks)
    detect_init_kernel<<<5, 256, 0, stream>>>(edge, batch, flags, bcursor, psum,
                                              W2l, W2r, W3l, W3r, wl2h, wr2h, wl3h, wr3h,
                                              E2, N, NGRAPHS, NB);

    // 2. Single-pass binned scatter (LDS-staged edges) into padded regions
    const int nblk = (E + EPB - 1) / EPB;   // 391
    const int scatter_lds = (2 * NB + 2 * EPB) * 4;
    bin_scatter_kernel<<<nblk, 256, scatter_lds, stream>>>(edge, flags, bcursor, entries, E, NB);

    // 3. Fused CSR finalize + layer 1 (fp16 + fp8 h1)
    csr_l1_kernel<<<NB, 256, 0, stream>>>(entries, bcursor, x, W1l, b1, W1r,
                                          rowptr, deg, csr, h1h, h1q, N, NB);

    const int fusedBlocks = (N + 31) / 32;   // 1563

    // 4. Layer 2 (fp8 gather + MFMA; writes fp16 + fp8 h2)
    gather_mfma_kernel<<<fusedBlocks, 256, 0, stream>>>(rowptr, deg, csr, h1q, h1h,
                                                        wl2h, b2, wr2h, h2h, h2q,
                                                        (float*)nullptr, nullptr, flags, N);

    // 5. Layer 3 (fp8 gather + MFMA + POOL epilogue; h3 never materialized)
    gather_mfma_kernel<<<fusedBlocks, 256, 0, stream>>>(rowptr, deg, csr, h2q, h2h,
                                                        wl3h, b3, wr3h, (__half*)nullptr,
                                                        (unsigned char*)nullptr,
                                                        psum, batch, flags, N);

    // 6. FC head (graph bounds via binary search in sorted batch)
    fc_kernel<<<NGRAPHS, 64, 0, stream>>>(psum, batch, flags, Wfc1, bfc1, Wfc2, bfc2, out, N);
}

// Round 19
// 202.979 us; speedup vs baseline: 1.3443x; 1.0306x over previous
//
#include <hip/hip_runtime.h>
#include <hip/hip_bf16.h>
#include <hip/hip_fp16.h>

#define HID 64
#define NGRAPHS 64
#define BUCKET 64        // nodes per bucket (dst >> 6)
#define CAP 4096         // padded entry slots per bucket (mean occupancy ~1024)
#define EPB 2048         // edges per block in bin_scatter (LDS-staged)
#define NSLOT 33         // pool LDS slots

typedef _Float16 half8 __attribute__((ext_vector_type(8)));
typedef float floatx4 __attribute__((ext_vector_type(4)));
typedef float floatx2 __attribute__((ext_vector_type(2)));

__device__ __forceinline__ unsigned char enc_fp8(float v) {
    int pk = __builtin_amdgcn_cvt_pk_fp8_f32(v, v, 0, false);
    return (unsigned char)(pk & 0xff);
}

__device__ __forceinline__ void cvt_acc16(float* bank, const uint4& u) {
    floatx2 p;
    p = __builtin_amdgcn_cvt_pk_f32_fp8(u.x, false); bank[0] += p[0];  bank[1] += p[1];
    p = __builtin_amdgcn_cvt_pk_f32_fp8(u.x, true);  bank[2] += p[0];  bank[3] += p[1];
    p = __builtin_amdgcn_cvt_pk_f32_fp8(u.y, false); bank[4] += p[0];  bank[5] += p[1];
    p = __builtin_amdgcn_cvt_pk_f32_fp8(u.y, true);  bank[6] += p[0];  bank[7] += p[1];
    p = __builtin_amdgcn_cvt_pk_f32_fp8(u.z, false); bank[8] += p[0];  bank[9] += p[1];
    p = __builtin_amdgcn_cvt_pk_f32_fp8(u.z, true);  bank[10] += p[0]; bank[11] += p[1];
    p = __builtin_amdgcn_cvt_pk_f32_fp8(u.w, false); bank[12] += p[0]; bank[13] += p[1];
    p = __builtin_amdgcn_cvt_pk_f32_fp8(u.w, true);  bank[14] += p[0]; bank[15] += p[1];
}

// ---------------------------------------------------------------------------
// Detect int64 vs int32, init cursors, zero psum, and convert weights to
// FRAGMENT-ORDERED fp16: dst[((kh*4+nt)*64+lane)*8+j] = W[k*64+col] where
// k = kh*32+(lane>>4)*8+j, col = nt*16+(lane&15). Phase-2 then loads each
// B-fragment as ONE lane-contiguous 16 B half8 (16 loads vs 256 strided).
// 5 blocks: block 0 = flags/cursors/psum; blocks 1-4 = one matrix each.
// ---------------------------------------------------------------------------
__global__ __launch_bounds__(256) void detect_init_kernel(const void* edge, const void* batch,
                                                          int* flags, int* bcursor,
                                                          float* psum,
                                                          const float* W2l, const float* W2r,
                                                          const float* W3l, const float* W3r,
                                                          __half* wl2f, __half* wr2f,
                                                          __half* wl3f, __half* wr3f,
                                                          int E2, int N, int G, int NB) {
    int t = threadIdx.x;
    int b = blockIdx.x;
    if (b == 0) {
        for (int i = t; i < NB; i += 256) bcursor[i] = i * CAP;
        for (int i = t; i < G * HID; i += 256) psum[i] = 0.0f;
        if (t < 64) {
            int lane = t;
            int half_ = E2 / 2;
            int stride = half_ / 64; if (stride < 1) stride = 1;
            int j = lane * stride; if (j >= half_) j = half_ - 1;
            long long v = ((const long long*)edge)[j];
            bool ok = (v >= 0 && v < (long long)N);
            unsigned long long m = __ballot(ok);
            if (lane == 0) flags[0] = (m == ~0ULL) ? 1 : 0;
            int halfB = N / 2;
            int strideB = halfB / 64; if (strideB < 1) strideB = 1;
            int jb = lane * strideB; if (jb >= halfB) jb = halfB - 1;
            long long vb = ((const long long*)batch)[jb];
            bool okb = (vb >= 0 && vb < (long long)G);
            unsigned long long mb = __ballot(okb);
            if (lane == 0) flags[1] = (mb == ~0ULL) ? 1 : 0;
        }
    } else {
        const float* src = (b == 1) ? W2l : (b == 2) ? W2r : (b == 3) ? W3l : W3r;
        __half* dst = (b == 1) ? wl2f : (b == 2) ? wr2f : (b == 3) ? wl3f : wr3f;
        for (int i = t; i < HID * HID; i += 256) {
            int j = i & 7;
            int lane = (i >> 3) & 63;
            int nt = (i >> 9) & 3;
            int kh = i >> 11;
            int k = kh * 32 + (lane >> 4) * 8 + j;
            int col = nt * 16 + (lane & 15);
            dst[i] = __float2half(src[k * HID + col]);
        }
    }
}

__device__ __forceinline__ int idx_at(const void* p, int i, bool is64) {
    return is64 ? (int)((const long long*)p)[i] : ((const int*)p)[i];
}

// ---------------------------------------------------------------------------
// Bucket scatter into PADDED per-bucket regions, single global read pass.
// ---------------------------------------------------------------------------
__global__ __launch_bounds__(256) void bin_scatter_kernel(const void* edge, const int* __restrict__ flags,
                                                          int* __restrict__ bcursor,
                                                          unsigned int* __restrict__ entries,
                                                          int E, int NB) {
    extern __shared__ int lds[];
    int* hist = lds;
    int* base = lds + NB;
    int* ssrc = lds + 2 * NB;
    int* sdst = ssrc + EPB;
    for (int i = threadIdx.x; i < NB; i += 256) hist[i] = 0;
    __syncthreads();
    bool is64 = flags[0] != 0;
    int start = blockIdx.x * EPB;
    int end = start + EPB; if (end > E) end = E;
    int cnt = end - start;
    for (int k = threadIdx.x; k < cnt; k += 256) {
        int e = start + k;
        int srcv = idx_at(edge, e, is64);
        int d = idx_at(edge, E + e, is64);
        ssrc[k] = srcv;
        sdst[k] = d;
        atomicAdd(&hist[d >> 6], 1);
    }
    __syncthreads();
    for (int i = threadIdx.x; i < NB; i += 256) {
        int h = hist[i];
        base[i] = h ? atomicAdd(&bcursor[i], h) : 0;
    }
    __syncthreads();
    for (int i = threadIdx.x; i < NB; i += 256) hist[i] = 0;
    __syncthreads();
    for (int k = threadIdx.x; k < cnt; k += 256) {
        int d = sdst[k];
        int b = d >> 6;
        int lo = atomicAdd(&hist[b], 1);
        int p = base[b] + lo;
        if (p < (b + 1) * CAP)
            entries[p] = ((unsigned int)ssrc[k] << 6) | (unsigned int)(d & 63);
    }
}

// ---------------------------------------------------------------------------
// Fused CSR finalize + LAYER 1. Outputs h1 fp16 + fp8.
// ---------------------------------------------------------------------------
__global__ __launch_bounds__(256) void csr_l1_kernel(const unsigned int* __restrict__ entries,
                                                     const int* __restrict__ bcursor,
                                                     const float* __restrict__ x,
                                                     const float* __restrict__ W1l,
                                                     const float* __restrict__ b1,
                                                     const float* __restrict__ W1r,
                                                     int* __restrict__ rowptr,
                                                     int* __restrict__ deg,
                                                     int* __restrict__ csr,
                                                     __half* __restrict__ h1h,
                                                     unsigned char* __restrict__ h1q,
                                                     int N, int NB) {
    __shared__ int hist[BUCKET];
    __shared__ int lstart[BUCKET];
    __shared__ int lcur[BUCKET];
    __shared__ float accx[BUCKET];
    __shared__ float sx[BUCKET];
    int t = threadIdx.x;
    int b = blockIdx.x;
    int r0 = b * CAP;
    int cnt = bcursor[b] - r0; if (cnt > CAP) cnt = CAP;
    if (t < BUCKET) {
        hist[t] = 0; lcur[t] = 0; accx[t] = 0.0f;
        int node = b * BUCKET + t;
        sx[t] = (node < N) ? x[node] : 0.0f;
    }
    __syncthreads();
    for (int j = r0 + t; j < r0 + cnt; j += 256) {
        unsigned int en = entries[j];
        atomicAdd(&hist[en & 63u], 1);
        atomicAdd(&accx[en & 63u], x[en >> 6]);
    }
    __syncthreads();
    if (t < BUCKET) {
        int v = hist[t];
        int s = v;
#pragma unroll
        for (int off = 1; off < 64; off <<= 1) {
            int u = __shfl_up(s, off);
            if (t >= off) s += u;
        }
        lstart[t] = s - v;
        int node = b * BUCKET + t;
        if (node < N) {
            rowptr[node] = r0 + s - v;
            deg[node] = v;
        }
    }
    __syncthreads();
    for (int j = r0 + t; j < r0 + cnt; j += 256) {
        unsigned int en = entries[j];
        int dl = (int)(en & 63u);
        int p = atomicAdd(&lcur[dl], 1);
        csr[r0 + lstart[dl] + p] = (int)(en >> 6);
    }
    __syncthreads();
    int f = t & 63;
    int sub = t >> 6;
    float wlf = W1l[f], bf = b1[f], wrf = W1r[f];
    for (int it = 0; it < 16; ++it) {
        int nl = it * 4 + sub;
        int node = b * BUCKET + nl;
        if (node < N) {
            int d = hist[nl];
            float mv = (d > 0) ? accx[nl] / (float)d : 0.0f;
            float xv = sx[nl];
            float v = fmaf(mv, wlf, fmaf(xv, wrf, bf));
            v = v > 0.0f ? v : 0.0f;
            float hv = v + xv;
            h1h[(size_t)node * HID + f] = __float2half(hv);
            h1q[(size_t)node * HID + f] = enc_fp8(hv);
        }
    }
}

// ---------------------------------------------------------------------------
// FUSED gather + MFMA node transform (+ optional pool epilogue).
// 64 nodes per 256-thread block (grid 782).
// Phase 1: 4 lanes/node, 16 B fp8 loads — ONE wave-instruction gathers 16
//   edges' full rows (halves VMEM instruction count vs 8-lane scheme).
// Phase 2: all 4 waves, 16 nodes each; fragment-ordered weights loaded as
//   lane-contiguous half8 (16 loads/lane). MFMA layouts per m89/m91.
// ---------------------------------------------------------------------------
__global__ __launch_bounds__(256) void gather_mfma_kernel(const int* __restrict__ rowptr,
                                                          const int* __restrict__ deg,
                                                          const int* __restrict__ csr,
                                                          const unsigned char* __restrict__ hq,
                                                          const __half* __restrict__ hph,
                                                          const __half* __restrict__ Wlf,
                                                          const float* __restrict__ bvec,
                                                          const __half* __restrict__ Wrf,
                                                          __half* __restrict__ houth,
                                                          unsigned char* __restrict__ houtq,
                                                          float* __restrict__ psum,
                                                          const void* batch,
                                                          const int* __restrict__ flags,
                                                          int N) {
    __shared__ _Float16 smean[64][HID + 8];   // 64 padded rows (144 B each)
    __shared__ float spool[NSLOT][HID];
    __shared__ int sb[64];
    int t = threadIdx.x;
    bool pool = (psum != nullptr);
    if (pool) {
        for (int i = t; i < NSLOT * HID; i += 256) ((float*)spool)[i] = 0.0f;
        if (t < 64) {
            int node = blockIdx.x * 64 + t;
            sb[t] = (node < N) ? idx_at(batch, node, flags[1] != 0) : -1;
        }
    }

    // ---- Phase 1: gather means from FP8 rows (4 lanes/node x 64 nodes) ----
    {
        int grp = t >> 2;        // 0..63 -> local node
        int l = t & 3;           // quarter: 16 features (16 B fp8)
        int i = blockIdx.x * 64 + grp;
        if (i < N) {
            int r0 = rowptr[i];
            int d = deg[i];
            int r1 = r0 + d;
            float a0[16], a1[16];
#pragma unroll
            for (int k = 0; k < 16; ++k) { a0[k] = 0.0f; a1[k] = 0.0f; }
            int j = r0;
            for (; j + 8 <= r1; j += 8) {
                uint4 u[8];
#pragma unroll
                for (int m = 0; m < 8; ++m) {
                    int s = csr[j + m];
                    u[m] = *(const uint4*)(hq + (size_t)s * HID + l * 16);
                }
#pragma unroll
                for (int m = 0; m < 8; ++m) cvt_acc16((m & 1) ? a1 : a0, u[m]);
            }
            for (; j < r1; ++j) {
                int s = csr[j];
                uint4 u0 = *(const uint4*)(hq + (size_t)s * HID + l * 16);
                cvt_acc16(a0, u0);
            }
            float inv = (d > 0) ? 1.0f / (float)d : 0.0f;
            __half2 o[8];
#pragma unroll
            for (int q = 0; q < 8; ++q)
                o[q] = __floats2half2_rn((a0[2 * q] + a1[2 * q]) * inv,
                                         (a0[2 * q + 1] + a1[2 * q + 1]) * inv);
            uint4* dst = (uint4*)&smean[grp][l * 16];
            dst[0] = ((uint4*)o)[0];
            dst[1] = ((uint4*)o)[1];
        }
    }
    __syncthreads();

    // ---- Phase 2: MFMA on all 4 waves (16 nodes each) ----
    int wave = t >> 6;
    int lane = t & 63;
    int m = lane & 15;
    int quad = lane >> 4;
    int node0 = blockIdx.x * 64 + wave * 16;
    if (node0 < N) {
        const _Float16* wlp = (const _Float16*)Wlf;
        const _Float16* wrp = (const _Float16*)Wrf;
        half8 bl[2][4], br[2][4];
#pragma unroll
        for (int kh = 0; kh < 2; ++kh)
#pragma unroll
            for (int nt = 0; nt < 4; ++nt) {
                size_t off = (size_t)((kh * 4 + nt) * 64 + lane) * 8;
                bl[kh][nt] = *(const half8*)(wlp + off);
                br[kh][nt] = *(const half8*)(wrp + off);
            }
        int nlA = wave * 16 + m;
        half8 am0 = *(const half8*)&smean[nlA][quad * 8];
        half8 am1 = *(const half8*)&smean[nlA][32 + quad * 8];
        int nodeA = node0 + m; if (nodeA >= N) nodeA = N - 1;
        const _Float16* hrow = (const _Float16*)hph + (size_t)nodeA * HID;
        half8 ah0 = *(const half8*)(hrow + quad * 8);
        half8 ah1 = *(const half8*)(hrow + 32 + quad * 8);

#pragma unroll
        for (int nt = 0; nt < 4; ++nt) {
            float b = bvec[nt * 16 + m];
            floatx4 c = {b, b, b, b};
            c = __builtin_amdgcn_mfma_f32_16x16x32_f16(am0, bl[0][nt], c, 0, 0, 0);
            c = __builtin_amdgcn_mfma_f32_16x16x32_f16(am1, bl[1][nt], c, 0, 0, 0);
            c = __builtin_amdgcn_mfma_f32_16x16x32_f16(ah0, br[0][nt], c, 0, 0, 0);
            c = __builtin_amdgcn_mfma_f32_16x16x32_f16(ah1, br[1][nt], c, 0, 0, 0);
            int f = nt * 16 + m;
#pragma unroll
            for (int r = 0; r < 4; ++r) {
                int nodeR = node0 + quad * 4 + r;
                if (nodeR < N) {
                    float v = c[r];
                    v = v > 0.0f ? v : 0.0f;
                    v += __half2float(((const __half*)hph)[(size_t)nodeR * HID + f]);
                    if (!pool) {
                        houth[(size_t)nodeR * HID + f] = __float2half(v);
                        houtq[(size_t)nodeR * HID + f] = enc_fp8(v);
                    } else {
                        int bg = sb[wave * 16 + quad * 4 + r];
                        int slot = bg - sb[0];
                        if (slot < NSLOT) atomicAdd(&spool[slot][f], v);
                        else atomicAdd(&psum[bg * HID + f], v);
                    }
                }
            }
        }
    }

    if (pool) {
        __syncthreads();
        int gbase = sb[0];
        for (int i = t; i < NSLOT * HID; i += 256) {
            int s = i >> 6, f = i & 63;
            float v = spool[s][f];
            if (v != 0.0f) atomicAdd(&psum[(gbase + s) * HID + f], v);
        }
    }
}

// ---------------------------------------------------------------------------
// FC head: one block (64 threads) per graph.
// ---------------------------------------------------------------------------
__device__ __forceinline__ int lbound(const void* batch, int n, long long key, bool is64) {
    int lo = 0, hi = n;
    while (lo < hi) {
        int mid = (lo + hi) >> 1;
        long long v = is64 ? ((const long long*)batch)[mid] : (long long)((const int*)batch)[mid];
        if (v < key) lo = mid + 1; else hi = mid;
    }
    return lo;
}

__global__ __launch_bounds__(64) void fc_kernel(const float* __restrict__ psum,
                                                const void* batch,
                                                const int* __restrict__ flags,
                                                const float* __restrict__ Wfc1,
                                                const float* __restrict__ bfc1,
                                                const float* __restrict__ Wfc2,
                                                const float* __restrict__ bfc2,
                                                float* __restrict__ out, int N) {
    __shared__ int sb2[2];
    __shared__ float mean[HID];
    int g = blockIdx.x;
    int t = threadIdx.x;
    bool is64 = flags[1] != 0;
    if (t == 0) sb2[0] = lbound(batch, N, g, is64);
    if (t == 1) sb2[1] = lbound(batch, N, g + 1, is64);
    __syncthreads();
    float c = fmaxf((float)(sb2[1] - sb2[0]), 1.0f);
    mean[t] = psum[g * HID + t] / c;
    __syncthreads();
    float v = 0.0f;
    if (t < 32) {
        float acc = bfc1[t];
#pragma unroll
        for (int k = 0; k < HID; ++k) acc += mean[k] * Wfc1[k * 32 + t];
        float hcc = acc > 0.0f ? acc : 0.0f;
        v = hcc * Wfc2[t];
    }
#pragma unroll
    for (int off = 32; off >= 1; off >>= 1) v += __shfl_down(v, off);
    if (t == 0) out[g] = v + bfc2[0];
}

extern "C" void kernel_launch(void* const* d_in, const int* in_sizes, int n_in,
                              void* d_out, int out_size, void* d_ws, size_t ws_size,
                              hipStream_t stream) {
    const int N = in_sizes[0];       // 50000
    const int E2 = in_sizes[1];      // 2*E
    const int E = E2 / 2;
    const int NB = (N + BUCKET - 1) / BUCKET;   // 782

    const float* x    = (const float*)d_in[0];
    const void*  edge = d_in[1];
    const void*  batch= d_in[2];
    const float* W1l  = (const float*)d_in[3];
    const float* b1   = (const float*)d_in[4];
    const float* W1r  = (const float*)d_in[5];
    const float* W2l  = (const float*)d_in[6];
    const float* b2   = (const float*)d_in[7];
    const float* W2r  = (const float*)d_in[8];
    const float* W3l  = (const float*)d_in[9];
    const float* b3   = (const float*)d_in[10];
    const float* W3r  = (const float*)d_in[11];
    const float* Wfc1 = (const float*)d_in[12];
    const float* bfc1 = (const float*)d_in[13];
    const float* Wfc2 = (const float*)d_in[14];
    const float* bfc2 = (const float*)d_in[15];
    float* out = (float*)d_out;

    // Workspace layout (256 B aligned slices). No host-side memsets.
    char* ws = (char*)d_ws;
    size_t o = 0;
    auto alloc = [&](size_t bytes) { char* p = ws + o; o += (bytes + 255) & ~(size_t)255; return p; };
    int*   bcursor = (int*)alloc((size_t)NB * 4);
    float* psum    = (float*)alloc((size_t)NGRAPHS * HID * 4);
    unsigned int* entries = (unsigned int*)alloc((size_t)NB * CAP * 4);
    int*   csr     = (int*)alloc((size_t)NB * CAP * 4);
    int*   rowptr  = (int*)alloc((size_t)N * 4);
    int*   deg     = (int*)alloc((size_t)N * 4);
    __half* h1h    = (__half*)alloc((size_t)N * HID * 2);
    __half* h2h    = (__half*)alloc((size_t)N * HID * 2);
    unsigned char* h1q = (unsigned char*)alloc((size_t)N * HID);
    unsigned char* h2q = (unsigned char*)alloc((size_t)N * HID);
    __half* wl2f   = (__half*)alloc((size_t)HID * HID * 2);  // fragment-ordered
    __half* wr2f   = (__half*)alloc((size_t)HID * HID * 2);
    __half* wl3f   = (__half*)alloc((size_t)HID * HID * 2);
    __half* wr3f   = (__half*)alloc((size_t)HID * HID * 2);
    int*   flags   = (int*)alloc(16);

    // 1. Detect + init + fragment-ordered fp16 weight convert (5 blocks)
    detect_init_kernel<<<5, 256, 0, stream>>>(edge, batch, flags, bcursor, psum,
                                              W2l, W2r, W3l, W3r, wl2f, wr2f, wl3f, wr3f,
                                              E2, N, NGRAPHS, NB);

    // 2. Single-pass binned scatter (LDS-staged edges) into padded regions
    const int nblk = (E + EPB - 1) / EPB;   // 391
    const int scatter_lds = (2 * NB + 2 * EPB) * 4;
    bin_scatter_kernel<<<nblk, 256, scatter_lds, stream>>>(edge, flags, bcursor, entries, E, NB);

    // 3. Fused CSR finalize + layer 1 (fp16 + fp8 h1)
    csr_l1_kernel<<<NB, 256, 0, stream>>>(entries, bcursor, x, W1l, b1, W1r,
                                          rowptr, deg, csr, h1h, h1q, N, NB);

    const int fusedBlocks = (N + 63) / 64;   // 782 (64 nodes per block)

    // 4. Layer 2 (fp8 gather + MFMA; writes fp16 + fp8 h2)
    gather_mfma_kernel<<<fusedBlocks, 256, 0, stream>>>(rowptr, deg, csr, h1q, h1h,
                                                        wl2f, b2, wr2f, h2h, h2q,
                                                        (float*)nullptr, nullptr, flags, N);

    // 5. Layer 3 (fp8 gather + MFMA + POOL epilogue)
    gather_mfma_kernel<<<fusedBlocks, 256, 0, stream>>>(rowptr, deg, csr, h2q, h2h,
                                                        wl3f, b3, wr3f, (__half*)nullptr,
                                                        (unsigned char*)nullptr,
                                                        psum, batch, flags, N);

    // 6. FC head
    fc_kernel<<<NGRAPHS, 64, 0, stream>>>(psum, batch, flags, Wfc1, bfc1, Wfc2, bfc2, out, N);
}

// Round 20
// 199.351 us; speedup vs baseline: 1.3687x; 1.0182x over previous
//
#include <hip/hip_runtime.h>
#include <hip/hip_bf16.h>
#include <hip/hip_fp16.h>

#define HID 64
#define NGRAPHS 64
#define BUCKET 64        // nodes per bucket (dst >> 6)
#define CAP 4096         // padded entry slots per bucket (mean occupancy ~1024)
#define EPB 2048         // edges per block in bin_scatter (LDS-staged)
#define NSLOT 33         // pool LDS slots

typedef _Float16 half8 __attribute__((ext_vector_type(8)));
typedef float floatx4 __attribute__((ext_vector_type(4)));
typedef float floatx2 __attribute__((ext_vector_type(2)));

__device__ __forceinline__ unsigned char enc_fp8(float v) {
    int pk = __builtin_amdgcn_cvt_pk_fp8_f32(v, v, 0, false);
    return (unsigned char)(pk & 0xff);
}

__device__ __forceinline__ void cvt_acc16(float* bank, const uint4& u) {
    floatx2 p;
    p = __builtin_amdgcn_cvt_pk_f32_fp8(u.x, false); bank[0] += p[0];  bank[1] += p[1];
    p = __builtin_amdgcn_cvt_pk_f32_fp8(u.x, true);  bank[2] += p[0];  bank[3] += p[1];
    p = __builtin_amdgcn_cvt_pk_f32_fp8(u.y, false); bank[4] += p[0];  bank[5] += p[1];
    p = __builtin_amdgcn_cvt_pk_f32_fp8(u.y, true);  bank[6] += p[0];  bank[7] += p[1];
    p = __builtin_amdgcn_cvt_pk_f32_fp8(u.z, false); bank[8] += p[0];  bank[9] += p[1];
    p = __builtin_amdgcn_cvt_pk_f32_fp8(u.z, true);  bank[10] += p[0]; bank[11] += p[1];
    p = __builtin_amdgcn_cvt_pk_f32_fp8(u.w, false); bank[12] += p[0]; bank[13] += p[1];
    p = __builtin_amdgcn_cvt_pk_f32_fp8(u.w, true);  bank[14] += p[0]; bank[15] += p[1];
}

// ---------------------------------------------------------------------------
// Detect int64 vs int32, init cursors, zero psum, fragment-ordered fp16
// weight convert. 5 blocks.
// ---------------------------------------------------------------------------
__global__ __launch_bounds__(256) void detect_init_kernel(const void* edge, const void* batch,
                                                          int* flags, int* bcursor,
                                                          float* psum,
                                                          const float* W2l, const float* W2r,
                                                          const float* W3l, const float* W3r,
                                                          __half* wl2f, __half* wr2f,
                                                          __half* wl3f, __half* wr3f,
                                                          int E2, int N, int G, int NB) {
    int t = threadIdx.x;
    int b = blockIdx.x;
    if (b == 0) {
        for (int i = t; i < NB; i += 256) bcursor[i] = i * CAP;
        for (int i = t; i < G * HID; i += 256) psum[i] = 0.0f;
        if (t < 64) {
            int lane = t;
            int half_ = E2 / 2;
            int stride = half_ / 64; if (stride < 1) stride = 1;
            int j = lane * stride; if (j >= half_) j = half_ - 1;
            long long v = ((const long long*)edge)[j];
            bool ok = (v >= 0 && v < (long long)N);
            unsigned long long m = __ballot(ok);
            if (lane == 0) flags[0] = (m == ~0ULL) ? 1 : 0;
            int halfB = N / 2;
            int strideB = halfB / 64; if (strideB < 1) strideB = 1;
            int jb = lane * strideB; if (jb >= halfB) jb = halfB - 1;
            long long vb = ((const long long*)batch)[jb];
            bool okb = (vb >= 0 && vb < (long long)G);
            unsigned long long mb = __ballot(okb);
            if (lane == 0) flags[1] = (mb == ~0ULL) ? 1 : 0;
        }
    } else {
        const float* src = (b == 1) ? W2l : (b == 2) ? W2r : (b == 3) ? W3l : W3r;
        __half* dst = (b == 1) ? wl2f : (b == 2) ? wr2f : (b == 3) ? wl3f : wr3f;
        for (int i = t; i < HID * HID; i += 256) {
            int j = i & 7;
            int lane = (i >> 3) & 63;
            int nt = (i >> 9) & 3;
            int kh = i >> 11;
            int k = kh * 32 + (lane >> 4) * 8 + j;
            int col = nt * 16 + (lane & 15);
            dst[i] = __float2half(src[k * HID + col]);
        }
    }
}

__device__ __forceinline__ int idx_at(const void* p, int i, bool is64) {
    return is64 ? (int)((const long long*)p)[i] : ((const int*)p)[i];
}

// ---------------------------------------------------------------------------
// Bucket scatter into PADDED per-bucket regions, single global read pass.
// ---------------------------------------------------------------------------
__global__ __launch_bounds__(256) void bin_scatter_kernel(const void* edge, const int* __restrict__ flags,
                                                          int* __restrict__ bcursor,
                                                          unsigned int* __restrict__ entries,
                                                          int E, int NB) {
    extern __shared__ int lds[];
    int* hist = lds;
    int* base = lds + NB;
    int* ssrc = lds + 2 * NB;
    int* sdst = ssrc + EPB;
    for (int i = threadIdx.x; i < NB; i += 256) hist[i] = 0;
    __syncthreads();
    bool is64 = flags[0] != 0;
    int start = blockIdx.x * EPB;
    int end = start + EPB; if (end > E) end = E;
    int cnt = end - start;
    for (int k = threadIdx.x; k < cnt; k += 256) {
        int e = start + k;
        int srcv = idx_at(edge, e, is64);
        int d = idx_at(edge, E + e, is64);
        ssrc[k] = srcv;
        sdst[k] = d;
        atomicAdd(&hist[d >> 6], 1);
    }
    __syncthreads();
    for (int i = threadIdx.x; i < NB; i += 256) {
        int h = hist[i];
        base[i] = h ? atomicAdd(&bcursor[i], h) : 0;
    }
    __syncthreads();
    for (int i = threadIdx.x; i < NB; i += 256) hist[i] = 0;
    __syncthreads();
    for (int k = threadIdx.x; k < cnt; k += 256) {
        int d = sdst[k];
        int b = d >> 6;
        int lo = atomicAdd(&hist[b], 1);
        int p = base[b] + lo;
        if (p < (b + 1) * CAP)
            entries[p] = ((unsigned int)ssrc[k] << 6) | (unsigned int)(d & 63);
    }
}

// ---------------------------------------------------------------------------
// Fused CSR finalize + LAYER 1. Outputs h1 fp16 + fp8.
// ---------------------------------------------------------------------------
__global__ __launch_bounds__(256) void csr_l1_kernel(const unsigned int* __restrict__ entries,
                                                     const int* __restrict__ bcursor,
                                                     const float* __restrict__ x,
                                                     const float* __restrict__ W1l,
                                                     const float* __restrict__ b1,
                                                     const float* __restrict__ W1r,
                                                     int* __restrict__ rowptr,
                                                     int* __restrict__ deg,
                                                     int* __restrict__ csr,
                                                     __half* __restrict__ h1h,
                                                     unsigned char* __restrict__ h1q,
                                                     int N, int NB) {
    __shared__ int hist[BUCKET];
    __shared__ int lstart[BUCKET];
    __shared__ int lcur[BUCKET];
    __shared__ float accx[BUCKET];
    __shared__ float sx[BUCKET];
    int t = threadIdx.x;
    int b = blockIdx.x;
    int r0 = b * CAP;
    int cnt = bcursor[b] - r0; if (cnt > CAP) cnt = CAP;
    if (t < BUCKET) {
        hist[t] = 0; lcur[t] = 0; accx[t] = 0.0f;
        int node = b * BUCKET + t;
        sx[t] = (node < N) ? x[node] : 0.0f;
    }
    __syncthreads();
    for (int j = r0 + t; j < r0 + cnt; j += 256) {
        unsigned int en = entries[j];
        atomicAdd(&hist[en & 63u], 1);
        atomicAdd(&accx[en & 63u], x[en >> 6]);
    }
    __syncthreads();
    if (t < BUCKET) {
        int v = hist[t];
        int s = v;
#pragma unroll
        for (int off = 1; off < 64; off <<= 1) {
            int u = __shfl_up(s, off);
            if (t >= off) s += u;
        }
        lstart[t] = s - v;
        int node = b * BUCKET + t;
        if (node < N) {
            rowptr[node] = r0 + s - v;
            deg[node] = v;
        }
    }
    __syncthreads();
    for (int j = r0 + t; j < r0 + cnt; j += 256) {
        unsigned int en = entries[j];
        int dl = (int)(en & 63u);
        int p = atomicAdd(&lcur[dl], 1);
        csr[r0 + lstart[dl] + p] = (int)(en >> 6);
    }
    __syncthreads();
    int f = t & 63;
    int sub = t >> 6;
    float wlf = W1l[f], bf = b1[f], wrf = W1r[f];
    for (int it = 0; it < 16; ++it) {
        int nl = it * 4 + sub;
        int node = b * BUCKET + nl;
        if (node < N) {
            int d = hist[nl];
            float mv = (d > 0) ? accx[nl] / (float)d : 0.0f;
            float xv = sx[nl];
            float v = fmaf(mv, wlf, fmaf(xv, wrf, bf));
            v = v > 0.0f ? v : 0.0f;
            float hv = v + xv;
            h1h[(size_t)node * HID + f] = __float2half(hv);
            h1q[(size_t)node * HID + f] = enc_fp8(hv);
        }
    }
}

// ---------------------------------------------------------------------------
// FUSED gather + MFMA node transform (+ optional pool epilogue).
// 64 nodes per 256-thread block (grid 782).
// Phase 1: 4 lanes/node, 16 B fp8 loads; main loop keeps 16 row-loads in
//   flight (vs 8) to double memory-level parallelism at the HBM-miss wall.
// Phase 2: all 4 waves, fragment-ordered weight loads (16/lane, contiguous).
// Dynamic LDS: layer 2 allocates only smean (9.2 KB -> ~2x blocks/CU).
// ---------------------------------------------------------------------------
__global__ __launch_bounds__(256) void gather_mfma_kernel(const int* __restrict__ rowptr,
                                                          const int* __restrict__ deg,
                                                          const int* __restrict__ csr,
                                                          const unsigned char* __restrict__ hq,
                                                          const __half* __restrict__ hph,
                                                          const __half* __restrict__ Wlf,
                                                          const float* __restrict__ bvec,
                                                          const __half* __restrict__ Wrf,
                                                          __half* __restrict__ houth,
                                                          unsigned char* __restrict__ houtq,
                                                          float* __restrict__ psum,
                                                          const void* batch,
                                                          const int* __restrict__ flags,
                                                          int N) {
    extern __shared__ char dynlds[];
    _Float16 (*smean)[HID + 8] = (_Float16 (*)[HID + 8])dynlds;      // 9216 B
    float (*spool)[HID] = (float (*)[HID])(dynlds + 64 * (HID + 8) * 2);
    int* sb = (int*)(dynlds + 64 * (HID + 8) * 2 + NSLOT * HID * 4);
    int t = threadIdx.x;
    bool pool = (psum != nullptr);
    if (pool) {
        for (int i = t; i < NSLOT * HID; i += 256) ((float*)spool)[i] = 0.0f;
        if (t < 64) {
            int node = blockIdx.x * 64 + t;
            sb[t] = (node < N) ? idx_at(batch, node, flags[1] != 0) : -1;
        }
    }

    // ---- Phase 1: gather means from FP8 rows (4 lanes/node x 64 nodes) ----
    {
        int grp = t >> 2;
        int l = t & 3;           // 16 features (16 B fp8) per lane
        int i = blockIdx.x * 64 + grp;
        if (i < N) {
            int r0 = rowptr[i];
            int d = deg[i];
            int r1 = r0 + d;
            float a0[16], a1[16];
#pragma unroll
            for (int k = 0; k < 16; ++k) { a0[k] = 0.0f; a1[k] = 0.0f; }
            int j = r0;
            // main loop: 16 independent loads in flight per trip
            for (; j + 16 <= r1; j += 16) {
                uint4 u[16];
#pragma unroll
                for (int m = 0; m < 16; ++m) {
                    int s = csr[j + m];
                    u[m] = *(const uint4*)(hq + (size_t)s * HID + l * 16);
                }
#pragma unroll
                for (int m = 0; m < 16; ++m) cvt_acc16((m & 1) ? a1 : a0, u[m]);
            }
            for (; j + 4 <= r1; j += 4) {
                uint4 u[4];
#pragma unroll
                for (int m = 0; m < 4; ++m) {
                    int s = csr[j + m];
                    u[m] = *(const uint4*)(hq + (size_t)s * HID + l * 16);
                }
#pragma unroll
                for (int m = 0; m < 4; ++m) cvt_acc16((m & 1) ? a1 : a0, u[m]);
            }
            for (; j < r1; ++j) {
                int s = csr[j];
                uint4 u0 = *(const uint4*)(hq + (size_t)s * HID + l * 16);
                cvt_acc16(a0, u0);
            }
            float inv = (d > 0) ? 1.0f / (float)d : 0.0f;
            __half2 o[8];
#pragma unroll
            for (int q = 0; q < 8; ++q)
                o[q] = __floats2half2_rn((a0[2 * q] + a1[2 * q]) * inv,
                                         (a0[2 * q + 1] + a1[2 * q + 1]) * inv);
            uint4* dst = (uint4*)&smean[grp][l * 16];
            dst[0] = ((uint4*)o)[0];
            dst[1] = ((uint4*)o)[1];
        }
    }
    __syncthreads();

    // ---- Phase 2: MFMA on all 4 waves (16 nodes each) ----
    int wave = t >> 6;
    int lane = t & 63;
    int m = lane & 15;
    int quad = lane >> 4;
    int node0 = blockIdx.x * 64 + wave * 16;
    if (node0 < N) {
        const _Float16* wlp = (const _Float16*)Wlf;
        const _Float16* wrp = (const _Float16*)Wrf;
        half8 bl[2][4], br[2][4];
#pragma unroll
        for (int kh = 0; kh < 2; ++kh)
#pragma unroll
            for (int nt = 0; nt < 4; ++nt) {
                size_t off = (size_t)((kh * 4 + nt) * 64 + lane) * 8;
                bl[kh][nt] = *(const half8*)(wlp + off);
                br[kh][nt] = *(const half8*)(wrp + off);
            }
        int nlA = wave * 16 + m;
        half8 am0 = *(const half8*)&smean[nlA][quad * 8];
        half8 am1 = *(const half8*)&smean[nlA][32 + quad * 8];
        int nodeA = node0 + m; if (nodeA >= N) nodeA = N - 1;
        const _Float16* hrow = (const _Float16*)hph + (size_t)nodeA * HID;
        half8 ah0 = *(const half8*)(hrow + quad * 8);
        half8 ah1 = *(const half8*)(hrow + 32 + quad * 8);

#pragma unroll
        for (int nt = 0; nt < 4; ++nt) {
            float b = bvec[nt * 16 + m];
            floatx4 c = {b, b, b, b};
            c = __builtin_amdgcn_mfma_f32_16x16x32_f16(am0, bl[0][nt], c, 0, 0, 0);
            c = __builtin_amdgcn_mfma_f32_16x16x32_f16(am1, bl[1][nt], c, 0, 0, 0);
            c = __builtin_amdgcn_mfma_f32_16x16x32_f16(ah0, br[0][nt], c, 0, 0, 0);
            c = __builtin_amdgcn_mfma_f32_16x16x32_f16(ah1, br[1][nt], c, 0, 0, 0);
            int f = nt * 16 + m;
#pragma unroll
            for (int r = 0; r < 4; ++r) {
                int nodeR = node0 + quad * 4 + r;
                if (nodeR < N) {
                    float v = c[r];
                    v = v > 0.0f ? v : 0.0f;
                    v += __half2float(((const __half*)hph)[(size_t)nodeR * HID + f]);
                    if (!pool) {
                        houth[(size_t)nodeR * HID + f] = __float2half(v);
                        houtq[(size_t)nodeR * HID + f] = enc_fp8(v);
                    } else {
                        int bg = sb[wave * 16 + quad * 4 + r];
                        int slot = bg - sb[0];
                        if (slot < NSLOT) atomicAdd(&spool[slot][f], v);
                        else atomicAdd(&psum[bg * HID + f], v);
                    }
                }
            }
        }
    }

    if (pool) {
        __syncthreads();
        int gbase = sb[0];
        for (int i = t; i < NSLOT * HID; i += 256) {
            int s = i >> 6, f = i & 63;
            float v = spool[s][f];
            if (v != 0.0f) atomicAdd(&psum[(gbase + s) * HID + f], v);
        }
    }
}

// ---------------------------------------------------------------------------
// FC head: one block (64 threads) per graph.
// ---------------------------------------------------------------------------
__device__ __forceinline__ int lbound(const void* batch, int n, long long key, bool is64) {
    int lo = 0, hi = n;
    while (lo < hi) {
        int mid = (lo + hi) >> 1;
        long long v = is64 ? ((const long long*)batch)[mid] : (long long)((const int*)batch)[mid];
        if (v < key) lo = mid + 1; else hi = mid;
    }
    return lo;
}

__global__ __launch_bounds__(64) void fc_kernel(const float* __restrict__ psum,
                                                const void* batch,
                                                const int* __restrict__ flags,
                                                const float* __restrict__ Wfc1,
                                                const float* __restrict__ bfc1,
                                                const float* __restrict__ Wfc2,
                                                const float* __restrict__ bfc2,
                                                float* __restrict__ out, int N) {
    __shared__ int sb2[2];
    __shared__ float mean[HID];
    int g = blockIdx.x;
    int t = threadIdx.x;
    bool is64 = flags[1] != 0;
    if (t == 0) sb2[0] = lbound(batch, N, g, is64);
    if (t == 1) sb2[1] = lbound(batch, N, g + 1, is64);
    __syncthreads();
    float c = fmaxf((float)(sb2[1] - sb2[0]), 1.0f);
    mean[t] = psum[g * HID + t] / c;
    __syncthreads();
    float v = 0.0f;
    if (t < 32) {
        float acc = bfc1[t];
#pragma unroll
        for (int k = 0; k < HID; ++k) acc += mean[k] * Wfc1[k * 32 + t];
        float hcc = acc > 0.0f ? acc : 0.0f;
        v = hcc * Wfc2[t];
    }
#pragma unroll
    for (int off = 32; off >= 1; off >>= 1) v += __shfl_down(v, off);
    if (t == 0) out[g] = v + bfc2[0];
}

extern "C" void kernel_launch(void* const* d_in, const int* in_sizes, int n_in,
                              void* d_out, int out_size, void* d_ws, size_t ws_size,
                              hipStream_t stream) {
    const int N = in_sizes[0];       // 50000
    const int E2 = in_sizes[1];      // 2*E
    const int E = E2 / 2;
    const int NB = (N + BUCKET - 1) / BUCKET;   // 782

    const float* x    = (const float*)d_in[0];
    const void*  edge = d_in[1];
    const void*  batch= d_in[2];
    const float* W1l  = (const float*)d_in[3];
    const float* b1   = (const float*)d_in[4];
    const float* W1r  = (const float*)d_in[5];
    const float* W2l  = (const float*)d_in[6];
    const float* b2   = (const float*)d_in[7];
    const float* W2r  = (const float*)d_in[8];
    const float* W3l  = (const float*)d_in[9];
    const float* b3   = (const float*)d_in[10];
    const float* W3r  = (const float*)d_in[11];
    const float* Wfc1 = (const float*)d_in[12];
    const float* bfc1 = (const float*)d_in[13];
    const float* Wfc2 = (const float*)d_in[14];
    const float* bfc2 = (const float*)d_in[15];
    float* out = (float*)d_out;

    // Workspace layout (256 B aligned slices). No host-side memsets.
    char* ws = (char*)d_ws;
    size_t o = 0;
    auto alloc = [&](size_t bytes) { char* p = ws + o; o += (bytes + 255) & ~(size_t)255; return p; };
    int*   bcursor = (int*)alloc((size_t)NB * 4);
    float* psum    = (float*)alloc((size_t)NGRAPHS * HID * 4);
    unsigned int* entries = (unsigned int*)alloc((size_t)NB * CAP * 4);
    int*   csr     = (int*)alloc((size_t)NB * CAP * 4);
    int*   rowptr  = (int*)alloc((size_t)N * 4);
    int*   deg     = (int*)alloc((size_t)N * 4);
    __half* h1h    = (__half*)alloc((size_t)N * HID * 2);
    __half* h2h    = (__half*)alloc((size_t)N * HID * 2);
    unsigned char* h1q = (unsigned char*)alloc((size_t)N * HID);
    unsigned char* h2q = (unsigned char*)alloc((size_t)N * HID);
    __half* wl2f   = (__half*)alloc((size_t)HID * HID * 2);  // fragment-ordered
    __half* wr2f   = (__half*)alloc((size_t)HID * HID * 2);
    __half* wl3f   = (__half*)alloc((size_t)HID * HID * 2);
    __half* wr3f   = (__half*)alloc((size_t)HID * HID * 2);
    int*   flags   = (int*)alloc(16);

    // 1. Detect + init + fragment-ordered fp16 weight convert (5 blocks)
    detect_init_kernel<<<5, 256, 0, stream>>>(edge, batch, flags, bcursor, psum,
                                              W2l, W2r, W3l, W3r, wl2f, wr2f, wl3f, wr3f,
                                              E2, N, NGRAPHS, NB);

    // 2. Single-pass binned scatter (LDS-staged edges) into padded regions
    const int nblk = (E + EPB - 1) / EPB;   // 391
    const int scatter_lds = (2 * NB + 2 * EPB) * 4;
    bin_scatter_kernel<<<nblk, 256, scatter_lds, stream>>>(edge, flags, bcursor, entries, E, NB);

    // 3. Fused CSR finalize + layer 1 (fp16 + fp8 h1)
    csr_l1_kernel<<<NB, 256, 0, stream>>>(entries, bcursor, x, W1l, b1, W1r,
                                          rowptr, deg, csr, h1h, h1q, N, NB);

    const int fusedBlocks = (N + 63) / 64;   // 782 (64 nodes per block)
    const int smeanBytes = 64 * (HID + 8) * 2;                     // 9216
    const int poolBytes  = smeanBytes + NSLOT * HID * 4 + 64 * 4;  // 17920

    // 4. Layer 2 (fp8 gather + MFMA; small LDS footprint -> higher occupancy)
    gather_mfma_kernel<<<fusedBlocks, 256, smeanBytes, stream>>>(rowptr, deg, csr, h1q, h1h,
                                                                 wl2f, b2, wr2f, h2h, h2q,
                                                                 (float*)nullptr, nullptr, flags, N);

    // 5. Layer 3 (fp8 gather + MFMA + POOL epilogue)
    gather_mfma_kernel<<<fusedBlocks, 256, poolBytes, stream>>>(rowptr, deg, csr, h2q, h2h,
                                                                wl3f, b3, wr3f, (__half*)nullptr,
                                                                (unsigned char*)nullptr,
                                                                psum, batch, flags, N);

    // 6. FC head
    fc_kernel<<<NGRAPHS, 64, 0, stream>>>(psum, batch, flags, Wfc1, bfc1, Wfc2, bfc2, out, N);
}